// Round 2
// baseline (625.515 us; speedup 1.0000x reference)
//
#include <hip/hip_runtime.h>
#include <stdint.h>

#define LDIFF 0.24f

constexpr int H = 512, W = 512, NB = 2;
constexpr int HW = H * W;              // 2^18
constexpr int N_D = NB * HW;           // 524288
constexpr int CVH = 511, CVW = 512;
constexpr int CHH = 512, CHW = 511;
constexpr int N_CV = NB * CVH * CVW;   // 523264
constexpr int NBLKS = 11;              // 11x11 blocks, step 48
constexpr int NBT = NB * 121;          // 242 workgroups <= 256 CUs -> co-resident

// LLC-coherent (cross-XCD) access: relaxed agent atomics = sc1 ops through the
// Infinity Cache. Validated in prior session R4-R9.
__device__ inline float ldc(const float* p) {
    return __hip_atomic_load(p, __ATOMIC_RELAXED, __HIP_MEMORY_SCOPE_AGENT);
}
__device__ inline void stc(float* p, float v) {
    __hip_atomic_store(p, v, __ATOMIC_RELAXED, __HIP_MEMORY_SCOPE_AGENT);
}
__device__ inline int ldci(const int* p) {
    return __hip_atomic_load(p, __ATOMIC_RELAXED, __HIP_MEMORY_SCOPE_AGENT);
}
__device__ inline void stci(int* p, int v) {
    __hip_atomic_store(p, v, __ATOMIC_RELAXED, __HIP_MEMORY_SCOPE_AGENT);
}

// wave64 DPP rotate/shift by 1 (VALU pipe, zero LDS traffic). Direction probed
// at runtime (dirL); the wavefront stencil's use (lf+rt) is direction-agnostic.
__device__ inline float rot_a(float x) {
    return __int_as_float(__builtin_amdgcn_update_dpp(0, __float_as_int(x), 0x134, 0xf, 0xf, false));
}
__device__ inline float rot_b(float x) {
    return __int_as_float(__builtin_amdgcn_update_dpp(0, __float_as_int(x), 0x13c, 0xf, 0xf, false));
}
__device__ inline float sh_a(float x) {
    return __int_as_float(__builtin_amdgcn_update_dpp(0, __float_as_int(x), 0x130, 0xf, 0xf, true));
}
__device__ inline float sh_b(float x) {
    return __int_as_float(__builtin_amdgcn_update_dpp(0, __float_as_int(x), 0x138, 0xf, 0xf, true));
}

// ======================= ONE kernel, zero global barriers =======================
//  A) per-block: local cv/ch halo tile (73x73) into LDS; disjoint cv/ch output
//     partition; params via wave butterfly; publish {cv_mean, ch_mean, cond}
//     + pflag (drained). A has NO cross-WG waits -> progress guaranteed.
//  B) ROW-LEADER wavefront: WG (i,0) processes blocks (i,0..10) sequentially.
//     L-dependency = in-LDS right-strip handoff (zero LLC traffic / zero poll).
//     Only the 10 row->row transitions (U/UR bottom strips via BSTR + wflag)
//     pay an LLC handoff: critical path 31*cB + 10*h instead of 31*(cB+h).
//     D holds exclusive 48x48 final cores only (cores tile the plane; (i,j) is
//     the last reference-order writer of its core).
//  C) diffusion 8 stages x 8 iters (R0-proven), t=1 waits 3x3 single wflags
//     (incl own: own core written by the leader), stages 2..8 dflag-chained.
__global__ __launch_bounds__(256) void kall(
    const float* __restrict__ guide, const float* __restrict__ initial,
    float* __restrict__ cv, float* __restrict__ ch,
    float* __restrict__ D, float* __restrict__ BSTR,
    float* __restrict__ T0, float* __restrict__ T1,
    float* __restrict__ ypred, int* __restrict__ sync_)
{
    __shared__ float cvT[73 * 74];
    __shared__ float chT[73 * 74];
    __shared__ float xT[2][4][64];
    __shared__ float xB[2][4][64];
    __shared__ float red[12];
    __shared__ float prmS[3];
    __shared__ float prm2[3];
    __shared__ float rstrip[64 * 16];   // previous block's blended right strip

    int* wflag = sync_;                 // [242] block B-done
    int* pflag = sync_ + 256;           // [242] params published
    int* dflag = sync_ + 1024;          // [242*16] diffusion stage counters
    float* PRM = (float*)(sync_ + 8192); // [242*4] {cv_mean, ch_mean, cond}

    const int blk = blockIdx.x;         // 0..120
    const int i = blk / NBLKS, j = blk % NBLKS;
    const int b = blockIdx.y;
    const int tid = threadIdx.x;
    const int lane = tid & 63, wv = tid >> 6;
    const int r0 = wv * 16;
    const int me = b * 121 + blk;

    const int y0 = i * 48, x0 = j * 48;
    const int y1 = min(y0 + 64, 512), x1 = min(x0 + 64, 512);
    const int bh = y1 - y0, bw = x1 - x0;
    const int yb = y0 - 8, xb = x0 - 8;
    const float kinv = 1.0f / (0.03f * 0.03f);

    // ===== A1: local cv/ch (rows yb..yb+72, cols xb..xb+72; 0 outside valid) =====
    const float* gb = guide + (size_t)b * 3 * HW;
    for (int p = tid; p < 73 * 73; p += 256) {
        int rr = p / 73, cc2 = p - rr * 73;
        int y = yb + rr, x = xb + cc2;
        float cvv = 0.0f, chv = 0.0f;
        if (y >= 0 && y < 512 && x >= 0 && x < 512) {
            const float* g = gb + y * W + x;
            float g0 = g[0], g1 = g[HW], g2 = g[2 * HW];
            if (y < 511) {
                float d = (fabsf(g[W] - g0) + fabsf(g[HW + W] - g1) + fabsf(g[2 * HW + W] - g2)) * (1.0f / 3.0f);
                cvv = 1.0f / (1.0f + d * d * kinv);
            }
            if (x < 511) {
                float d = (fabsf(g[1] - g0) + fabsf(g[HW + 1] - g1) + fabsf(g[2 * HW + 1] - g2)) * (1.0f / 3.0f);
                chv = 1.0f / (1.0f + d * d * kinv);
            }
        }
        cvT[rr * 74 + cc2] = cvv;
        chT[rr * 74 + cc2] = chv;
    }
    __syncthreads();

    // ===== A2: write disjoint cv/ch output partitions (48x48 cores) =====
    {
        int rcv = min(y0 + 48, CVH) - y0, ccv = min(x0 + 48, CVW) - x0;
        float* cvo = cv + b * CVH * CVW;
        for (int p = tid; p < rcv * ccv; p += 256) {
            int r = p / ccv, c = p - r * ccv;
            cvo[(y0 + r) * CVW + x0 + c] = cvT[(r + 8) * 74 + c + 8];
        }
        int rch = min(y0 + 48, CHH) - y0, cch = min(x0 + 48, CHW) - x0;
        float* cho = ch + b * CHH * CHW;
        for (int p = tid; p < rch * cch; p += 256) {
            int r = p / cch, c = p - r * cch;
            cho[(y0 + r) * CHW + x0 + c] = chT[(r + 8) * 74 + c + 8];
        }
    }

    // ===== A3: params — wave butterfly + 1 barrier =====
    float scv = 0.f, sch = 0.f, sun = 0.f;
    {
        int n = (bh - 1) * bw;
        for (int p = tid; p < n; p += 256) { int r = p / bw, c = p - r * bw; scv += cvT[(r + 8) * 74 + c + 8]; }
    }
    {
        int cols = bw - 1, n = bh * cols;
        for (int p = tid; p < n; p += 256) { int r = p / cols, c = p - r * cols; sch += chT[(r + 8) * 74 + c + 8]; }
    }
    const int ur = min(y1, 511) - y0, uc = min(x1, 511) - x0;
    {
        int n = ur * uc;
        for (int p = tid; p < n; p += 256) {
            int r = p / uc, c = p - r * uc;
            float s1 = 0.f, s2 = 0.f, t1 = 0.f, t2 = 0.f;
            #pragma unroll
            for (int dy = 0; dy < 3; dy++)
                #pragma unroll
                for (int dx = 0; dx < 3; dx++) {
                    float v = cvT[(r + 7 + dy) * 74 + c + 7 + dx]; s1 += v; s2 += v * v;
                    float w2 = chT[(r + 7 + dy) * 74 + c + 7 + dx]; t1 += w2; t2 += w2 * w2;
                }
            float m = s1 * (1.0f / 9.0f);
            float vcv = s2 * (1.0f / 9.0f) - m * m;
            m = t1 * (1.0f / 9.0f);
            float vch = t2 * (1.0f / 9.0f) - m * m;
            if (vcv < 0.1f && vch < 0.1f) sun += 1.f;
        }
    }
    #pragma unroll
    for (int m = 1; m < 64; m <<= 1) {
        scv += __shfl_xor(scv, m);
        sch += __shfl_xor(sch, m);
        sun += __shfl_xor(sun, m);
    }
    if (lane == 0) { red[wv * 3] = scv; red[wv * 3 + 1] = sch; red[wv * 3 + 2] = sun; }
    __syncthreads();
    if (tid == 0) {
        float a0 = red[0] + red[3] + red[6] + red[9];
        float a1 = red[1] + red[4] + red[7] + red[10];
        float a2 = red[2] + red[5] + red[8] + red[11];
        prmS[0] = a0 / (float)((bh - 1) * bw);
        prmS[1] = a1 / (float)(bh * (bw - 1));
        prmS[2] = (a2 / (float)(ur * uc) > 0.7f) ? 1.0f : 0.0f;
        // publish params for the row leader
        stc(&PRM[me * 4 + 0], prmS[0]);
        stc(&PRM[me * 4 + 1], prmS[1]);
        stc(&PRM[me * 4 + 2], prmS[2]);
    }
    __syncthreads();
    asm volatile("s_waitcnt vmcnt(0)" ::: "memory");  // wave0 drains PRM stores
    if (tid == 0) stci(&pflag[me], 1);

    // DPP direction probe (wave-uniform)
    int prb = __builtin_amdgcn_update_dpp(0, lane, 0x134, 0xf, 0xf, false);
    const bool dirL = (prb == ((lane + 63) & 63));

    float* Db = D + b * HW;
    const float* ini = initial + b * HW;

    // ===== B: row-leader wavefront =====
    if (j == 0) {
        const int mh = bh - 1;
        for (int jb = 0; jb < NBLKS; ++jb) {
            const int xj = jb * 48;
            const int bwj = min(xj + 64, 512) - xj;
            const int mwj = bwj - 1;
            const int ccw = lane & mwj;
            const int gme = me + jb;
            const int meU = gme - NBLKS;
            if (tid == 0) {
                if (jb > 0) {
                    while (ldci(&pflag[gme]) == 0) __builtin_amdgcn_s_sleep(0);
                    prm2[0] = ldc(&PRM[gme * 4]);
                    prm2[1] = ldc(&PRM[gme * 4 + 1]);
                    prm2[2] = ldc(&PRM[gme * 4 + 2]);
                } else {
                    prm2[0] = prmS[0]; prm2[1] = prmS[1]; prm2[2] = prmS[2];
                }
                if (i > 0) {
                    while (ldci(&wflag[meU]) == 0) __builtin_amdgcn_s_sleep(0);
                    if (jb < NBLKS - 1)
                        while (ldci(&wflag[meU + 1]) == 0) __builtin_amdgcn_s_sleep(0);
                }
            }
            __syncthreads();
            const bool condj = prm2[2] > 0.5f;
            const float aj = LDIFF * prm2[0], bcj = LDIFF * prm2[1];

            // orig sources (last reference-order writer before (i,jb)):
            //   c<16 & jb>0          -> previous block's right strip (LDS)
            //   r<16 & i>0 & c>=48   -> UR bottom strip (BSTR)
            //   r<16 & i>0 & c<48    -> U  bottom strip (BSTR)
            //   else                 -> initial
            float u[16], orig[16];
            #pragma unroll
            for (int k = 0; k < 16; k++) {
                int rr = (r0 + k) & mh;
                if (jb > 0 && ccw < 16)
                    orig[k] = rstrip[rr * 16 + ccw];
                else if (i > 0 && rr < 16)
                    orig[k] = (ccw >= 48) ? ldc(&BSTR[(size_t)(meU + 1) * 1024 + rr * 64 + (ccw - 48)])
                                          : ldc(&BSTR[(size_t)meU * 1024 + rr * 64 + ccw]);
                else
                    orig[k] = ini[(y0 + rr) * W + xj + ccw];
                u[k] = orig[k];
            }

            if (condj) {
                int bs = 0;
                for (int it = 0; it < 10; it++) {
                    xT[bs][wv][lane] = u[0];
                    xB[bs][wv][lane] = u[15];
                    __syncthreads();
                    float ub = xB[bs][(wv + 3) & 3][lane];   // row r0-1 (periodic)
                    float ut = xT[bs][(wv + 1) & 3][lane];   // row r0+16 (periodic)
                    float nu[16];
                    #pragma unroll
                    for (int k = 0; k < 16; k++) {
                        float up = (k == 0) ? ub : u[k - 1];
                        float dn = (k == 15) ? ut : u[k + 1];
                        float hsum = rot_a(u[k]) + rot_b(u[k]);
                        nu[k] = u[k] + aj * (up + dn - 2.0f * u[k]) + bcj * (hsum - 2.0f * u[k]);
                    }
                    #pragma unroll
                    for (int k = 0; k < 16; k++) u[k] = nu[k];
                    bs ^= 1;
                }
                // blend
                #pragma unroll
                for (int k = 0; k < 16; k++) {
                    int r = r0 + k;
                    if (r < bh && lane < bwj) {
                        float byw = (y0 > 0 && r < 16) ? (float)r * (1.0f / 16.0f) : 1.0f;
                        float bxw = (xj > 0 && lane < 16) ? (float)lane * (1.0f / 16.0f) : 1.0f;
                        float wgt = byw * bxw;
                        u[k] = orig[k] * (1.0f - wgt) + u[k] * wgt;
                    }
                }
            }
            __syncthreads();   // rstrip read complete before overwrite

            #pragma unroll
            for (int k = 0; k < 16; k++) {
                int r = r0 + k;
                if (r < bh && lane < bwj) {
                    if (jb < NBLKS - 1 && lane >= 48) rstrip[r * 16 + (lane - 48)] = u[k];
                    if (i < NBLKS - 1 && r >= 48)
                        stc(&BSTR[(size_t)gme * 1024 + (r - 48) * 64 + lane], u[k]);
                    if (r < 48 && lane < 48)
                        stc(&Db[(y0 + r) * W + xj + lane], u[k]);
                }
            }
            asm volatile("s_waitcnt vmcnt(0)" ::: "memory");  // per-wave drain
            __syncthreads();   // all waves drained + rstrip visible
            if (tid == 0) stci(&wflag[gme], 1);
        }
    }

    // ===== C: diffusion, 8 stages x 8 iters =====
    const int cx = xb + lane;
    const int gxc = min(max(cx, 0), 511);
    float cvr[16], chr[16], chl[16];
    int gyA[16];
    #pragma unroll
    for (int k = 0; k < 16; k++) {
        int cy = yb + r0 + k;
        gyA[k] = min(max(cy, 0), 511);
        cvr[k] = cvT[(r0 + k) * 74 + lane];    // 0 outside valid by construction
        chr[k] = chT[(r0 + k) * 74 + lane];
        chl[k] = dirL ? sh_a(chr[k]) : sh_b(chr[k]);   // lane0 -> 0 (halo col)
    }
    const float cvm1 = (wv == 0) ? 0.0f : cvT[(r0 - 1) * 74 + lane];

    float* Tb0 = T0 + b * HW;
    float* Tb1 = T1 + b * HW;
    float* ypb = ypred + b * HW;
    const bool cok = (lane >= 8 && lane < 56 && xb + lane < 512);

    for (int t = 1; t <= 8; t++) {
        const float* src = (t == 1) ? Db : (((t - 1) & 1) ? Tb1 : Tb0);
        if (wv == 0) {
            bool need = false;
            const int* fp = wflag;
            int thr = 1;
            if (t == 1) {
                if (lane < 9) {                       // 3x3 incl center (own core
                    int di = lane / 3 - 1, dj = lane % 3 - 1;   // written by leader)
                    int ni = i + di, nj = j + dj;
                    if (ni >= 0 && ni < NBLKS && nj >= 0 && nj < NBLKS) {
                        need = true;
                        fp = &wflag[b * 121 + ni * NBLKS + nj];
                    }
                }
            } else {
                thr = t - 1;
                if (lane < 9) {
                    int di = lane / 3 - 1, dj = lane % 3 - 1;
                    int ni = i + di, nj = j + dj;
                    if ((di | dj) != 0 && ni >= 0 && ni < NBLKS && nj >= 0 && nj < NBLKS) {
                        need = true;
                        fp = &dflag[(b * 121 + ni * NBLKS + nj) * 16];
                    }
                }
            }
            while (true) {
                int v = need ? ldci(fp) : 0x7fffffff;
                if (__ballot(v < thr) == 0) break;
                __builtin_amdgcn_s_sleep(8);
            }
        }
        __syncthreads();
        float uq[16];
        #pragma unroll
        for (int k = 0; k < 16; k++) uq[k] = ldc(&src[gyA[k] * W + gxc]);

        int bs = 0;
        for (int it = 0; it < 8; it++) {
            xT[bs][wv][lane] = uq[0];
            xB[bs][wv][lane] = uq[15];
            __syncthreads();
            float ub = (wv > 0) ? xB[bs][wv - 1][lane] : uq[0];
            float ut = (wv < 3) ? xT[bs][wv + 1][lane] : uq[15];
            float V[16];
            #pragma unroll
            for (int k = 0; k < 16; k++) {
                float up = (k == 0) ? ub : uq[k - 1];
                float dn = (k == 15) ? ut : uq[k + 1];
                float cup = (k == 0) ? cvm1 : cvr[k - 1];
                V[k] = uq[k] + LDIFF * cvr[k] * (dn - uq[k]) - LDIFF * cup * (uq[k] - up);
            }
            #pragma unroll
            for (int k = 0; k < 16; k++) {
                float rA = rot_a(V[k]);
                float rB = rot_b(V[k]);
                float lf = dirL ? rA : rB;
                float rt = dirL ? rB : rA;
                uq[k] = V[k] + LDIFF * chr[k] * (rt - V[k]) - LDIFF * chl[k] * (V[k] - lf);
            }
            bs ^= 1;
        }

        if (t < 8) {
            float* dst = (t & 1) ? Tb1 : Tb0;
            if (cok) {
                #pragma unroll
                for (int k = 0; k < 16; k++) {
                    int r = r0 + k;
                    if (r >= 8 && r < 56) {
                        int y = yb + r;
                        if (y < 512) stc(&dst[y * W + xb + lane], uq[k]);
                    }
                }
            }
            asm volatile("s_waitcnt vmcnt(0)" ::: "memory");
            __syncthreads();
            if (tid == 0) stci(&dflag[me * 16], t);
        } else {
            if (cok) {
                #pragma unroll
                for (int k = 0; k < 16; k++) {
                    int r = r0 + k;
                    if (r >= 8 && r < 56) {
                        int y = yb + r;
                        if (y < 512) ypb[y * W + xb + lane] = uq[k];
                    }
                }
            }
        }
    }
}

extern "C" void kernel_launch(void* const* d_in, const int* in_sizes, int n_in,
                              void* d_out, int out_size, void* d_ws, size_t ws_size,
                              hipStream_t stream) {
    const float* guide   = (const float*)d_in[0];
    const float* initial = (const float*)d_in[1];
    float* y_pred = (float*)d_out;
    float* cv = y_pred + N_D;          // output 1
    float* ch = cv + N_CV;             // output 2

    uint8_t* w = (uint8_t*)d_ws;
    int* sync_ = (int*)w;                                  // 64 KB flag/param area
    float* D    = (float*)(w + 65536);                     // 2 MB final cores
    float* BSTR = D + N_D;                                 // 242 * 1 KB bottom strips
    float* T0   = BSTR + (size_t)NBT * 1024;
    float* T1   = T0 + N_D;
    // total ws use: 64 KB + 2 MB + ~1 MB + 2*2 MB ~= 7 MB

    (void)hipMemsetAsync(sync_, 0, 65536, stream);
    kall<<<dim3(121, NB), 256, 0, stream>>>(guide, initial, cv, ch, D, BSTR, T0, T1, y_pred, sync_);
}

// Round 3
// 384.258 us; speedup vs baseline: 1.6278x; 1.6278x over previous
//
#include <hip/hip_runtime.h>
#include <stdint.h>

#define LDIFF 0.24f

constexpr int H = 512, W = 512, NB = 2;
constexpr int HW = H * W;              // 2^18
constexpr int N_D = NB * HW;           // 524288
constexpr int CVH = 511, CVW = 512;
constexpr int CHH = 512, CHW = 511;
constexpr int N_CV = NB * CVH * CVW;   // 523264
constexpr int NBLKS = 11;              // 11x11 blocks, step 48
constexpr int NBT = NB * 121;          // 242 workgroups <= 256 CUs -> co-resident

// LLC-coherent (cross-XCD) access: relaxed agent atomics = sc1 ops through the
// Infinity Cache. Validated in prior session R4-R9.
__device__ inline float ldc(const float* p) {
    return __hip_atomic_load(p, __ATOMIC_RELAXED, __HIP_MEMORY_SCOPE_AGENT);
}
__device__ inline void stc(float* p, float v) {
    __hip_atomic_store(p, v, __ATOMIC_RELAXED, __HIP_MEMORY_SCOPE_AGENT);
}
__device__ inline int ldci(const int* p) {
    return __hip_atomic_load(p, __ATOMIC_RELAXED, __HIP_MEMORY_SCOPE_AGENT);
}
__device__ inline void stci(int* p, int v) {
    __hip_atomic_store(p, v, __ATOMIC_RELAXED, __HIP_MEMORY_SCOPE_AGENT);
}

// wave64 DPP rotate/shift by 1 (VALU pipe, zero LDS traffic). Direction probed
// at runtime (dirL); the wavefront stencil's use (lf+rt) is direction-agnostic.
__device__ inline float rot_a(float x) {
    return __int_as_float(__builtin_amdgcn_update_dpp(0, __float_as_int(x), 0x134, 0xf, 0xf, false));
}
__device__ inline float rot_b(float x) {
    return __int_as_float(__builtin_amdgcn_update_dpp(0, __float_as_int(x), 0x13c, 0xf, 0xf, false));
}
__device__ inline float sh_a(float x) {
    return __int_as_float(__builtin_amdgcn_update_dpp(0, __float_as_int(x), 0x130, 0xf, 0xf, true));
}
__device__ inline float sh_b(float x) {
    return __int_as_float(__builtin_amdgcn_update_dpp(0, __float_as_int(x), 0x138, 0xf, 0xf, true));
}

// ======================= ONE kernel, zero global barriers =======================
//  A) per-block: local cv/ch halo tile (73x73) into LDS; disjoint cv/ch output
//     partition; params via wave butterfly. No cross-WG waits in A.
//  B) interleaved wavefront (R0 structure) with STRIP-SENTINEL handoff:
//     producer publishes right (64x16) / bottom (16x64) strips into per-block
//     edge buffers (sentinel 0xFFFFFFFF-initialized) with NO drain and NO flag
//     on the chain. Consumer lanes poll only their own strip words: coarse
//     poll of 1 representative word/lane (s_sleep(8)) -> fine verify-all.
//     Removes 2 of 3 LLC round-trips per chain step vs the flag scheme.
//     D holds exclusive 48x48 final cores (cores tile the plane; each block is
//     the last reference-order writer of its core). wflag (for C) set after
//     full drain + barrier — off the B chain.
//  C) diffusion 8 stages x 8 iters (proven): t=1 waits 3x3 wflag incl center;
//     stages 2..8 dflag-chained. Flag-based on purpose — R1 showed whole-tile
//     sentinel polling here floods the LLC with atomic traffic.
__global__ __launch_bounds__(256) void kall(
    const float* __restrict__ guide, const float* __restrict__ initial,
    float* __restrict__ cv, float* __restrict__ ch,
    float* __restrict__ D, float* __restrict__ EDG,
    float* __restrict__ T0, float* __restrict__ T1,
    float* __restrict__ ypred, int* __restrict__ sync_)
{
    __shared__ float cvT[73 * 74];
    __shared__ float chT[73 * 74];
    __shared__ float xT[2][4][64];
    __shared__ float xB[2][4][64];
    __shared__ float red[12];
    __shared__ float prmS[3];

    int* wflag = sync_;                 // [242] block B-done (gates C t=1)
    int* dflag = sync_ + 1024;          // [242*16] diffusion stage counters

    const int blk = blockIdx.x;         // 0..120
    const int i = blk / NBLKS, j = blk % NBLKS;
    const int b = blockIdx.y;
    const int tid = threadIdx.x;
    const int lane = tid & 63, wv = tid >> 6;
    const int r0 = wv * 16;
    const int me = b * 121 + blk;

    const int y0 = i * 48, x0 = j * 48;
    const int y1 = min(y0 + 64, 512), x1 = min(x0 + 64, 512);
    const int bh = y1 - y0, bw = x1 - x0;
    const int yb = y0 - 8, xb = x0 - 8;
    const float kinv = 1.0f / (0.03f * 0.03f);

    // ===== A1: local cv/ch (rows yb..yb+72, cols xb..xb+72; 0 outside valid) =====
    const float* gb = guide + (size_t)b * 3 * HW;
    for (int p = tid; p < 73 * 73; p += 256) {
        int rr = p / 73, cc2 = p - rr * 73;
        int y = yb + rr, x = xb + cc2;
        float cvv = 0.0f, chv = 0.0f;
        if (y >= 0 && y < 512 && x >= 0 && x < 512) {
            const float* g = gb + y * W + x;
            float g0 = g[0], g1 = g[HW], g2 = g[2 * HW];
            if (y < 511) {
                float d = (fabsf(g[W] - g0) + fabsf(g[HW + W] - g1) + fabsf(g[2 * HW + W] - g2)) * (1.0f / 3.0f);
                cvv = 1.0f / (1.0f + d * d * kinv);
            }
            if (x < 511) {
                float d = (fabsf(g[1] - g0) + fabsf(g[HW + 1] - g1) + fabsf(g[2 * HW + 1] - g2)) * (1.0f / 3.0f);
                chv = 1.0f / (1.0f + d * d * kinv);
            }
        }
        cvT[rr * 74 + cc2] = cvv;
        chT[rr * 74 + cc2] = chv;
    }
    __syncthreads();

    // ===== A2: write disjoint cv/ch output partitions (48x48 cores) =====
    {
        int rcv = min(y0 + 48, CVH) - y0, ccv = min(x0 + 48, CVW) - x0;
        float* cvo = cv + b * CVH * CVW;
        for (int p = tid; p < rcv * ccv; p += 256) {
            int r = p / ccv, c = p - r * ccv;
            cvo[(y0 + r) * CVW + x0 + c] = cvT[(r + 8) * 74 + c + 8];
        }
        int rch = min(y0 + 48, CHH) - y0, cch = min(x0 + 48, CHW) - x0;
        float* cho = ch + b * CHH * CHW;
        for (int p = tid; p < rch * cch; p += 256) {
            int r = p / cch, c = p - r * cch;
            cho[(y0 + r) * CHW + x0 + c] = chT[(r + 8) * 74 + c + 8];
        }
    }

    // ===== A3: params — wave butterfly + 1 barrier =====
    float scv = 0.f, sch = 0.f, sun = 0.f;
    {
        int n = (bh - 1) * bw;
        for (int p = tid; p < n; p += 256) { int r = p / bw, c = p - r * bw; scv += cvT[(r + 8) * 74 + c + 8]; }
    }
    {
        int cols = bw - 1, n = bh * cols;
        for (int p = tid; p < n; p += 256) { int r = p / cols, c = p - r * cols; sch += chT[(r + 8) * 74 + c + 8]; }
    }
    const int ur = min(y1, 511) - y0, uc = min(x1, 511) - x0;
    {
        int n = ur * uc;
        for (int p = tid; p < n; p += 256) {
            int r = p / uc, c = p - r * uc;
            float s1 = 0.f, s2 = 0.f, t1 = 0.f, t2 = 0.f;
            #pragma unroll
            for (int dy = 0; dy < 3; dy++)
                #pragma unroll
                for (int dx = 0; dx < 3; dx++) {
                    float v = cvT[(r + 7 + dy) * 74 + c + 7 + dx]; s1 += v; s2 += v * v;
                    float w2 = chT[(r + 7 + dy) * 74 + c + 7 + dx]; t1 += w2; t2 += w2 * w2;
                }
            float m = s1 * (1.0f / 9.0f);
            float vcv = s2 * (1.0f / 9.0f) - m * m;
            m = t1 * (1.0f / 9.0f);
            float vch = t2 * (1.0f / 9.0f) - m * m;
            if (vcv < 0.1f && vch < 0.1f) sun += 1.f;
        }
    }
    #pragma unroll
    for (int m = 1; m < 64; m <<= 1) {
        scv += __shfl_xor(scv, m);
        sch += __shfl_xor(sch, m);
        sun += __shfl_xor(sun, m);
    }
    if (lane == 0) { red[wv * 3] = scv; red[wv * 3 + 1] = sch; red[wv * 3 + 2] = sun; }
    __syncthreads();
    if (tid == 0) {
        float a0 = red[0] + red[3] + red[6] + red[9];
        float a1 = red[1] + red[4] + red[7] + red[10];
        float a2 = red[2] + red[5] + red[8] + red[11];
        prmS[0] = a0 / (float)((bh - 1) * bw);
        prmS[1] = a1 / (float)(bh * (bw - 1));
        prmS[2] = (a2 / (float)(ur * uc) > 0.7f) ? 1.0f : 0.0f;
    }
    __syncthreads();

    // DPP direction probe (wave-uniform)
    int prb = __builtin_amdgcn_update_dpp(0, lane, 0x134, 0xf, 0xf, false);
    const bool dirL = (prb == ((lane + 63) & 63));

    const bool cond = prmS[2] > 0.5f;
    const float a = LDIFF * prmS[0], bc = LDIFF * prmS[1];
    float* Db = D + b * HW;
    const float* ini = initial + b * HW;
    float* RG = EDG + (size_t)me * 2048;        // my right strip  [64][16]
    float* BG = RG + 1024;                      // my bottom strip [16][64]

    // ===== B: wavefront, strip-sentinel handoff =====
    const int mh = bh - 1, mw = bw - 1;
    const int ccw = lane & mw;
    const int rr0 = r0 & mh;     // rr = rr0 + k for k=0..15 (no wrap within run)

    float u[16], orig[16];
    {
        // Per-lane source of orig (= last writer before me in reference
        // row-major order); k-INDEPENDENT per lane:
        //   c<16, j>0            -> L's right strip  (stride 16)
        //   rr0<16, i>0, c>=48   -> UR's bottom strip (stride 64)
        //   rr0<16, i>0, c<48    -> U's bottom strip  (stride 64)
        //   else                 -> initial
        const int* sp0 = nullptr; int strd = 0;
        if (j > 0 && ccw < 16) {
            sp0 = (const int*)(EDG + (size_t)(me - 1) * 2048 + rr0 * 16 + ccw);
            strd = 16;
        } else if (i > 0 && rr0 < 16) {
            sp0 = (ccw >= 48) ? (const int*)(EDG + (size_t)(me - NBLKS + 1) * 2048 + 1024 + (ccw - 48))
                              : (const int*)(EDG + (size_t)(me - NBLKS) * 2048 + 1024 + ccw);
            strd = 64;
        }
        if (!sp0) {
            #pragma unroll
            for (int k = 0; k < 16; k++) orig[k] = ini[(y0 + rr0 + k) * W + x0 + ccw];
        } else {
            // coarse: poll the producer's last-issued word for this lane
            const int* spL = sp0 + 15 * strd;
            while (ldci(spL) == -1) __builtin_amdgcn_s_sleep(8);
            // fine: gather all 16, re-poll stragglers (OOO store completion)
            uint32_t pend = 0xFFFFu;
            while (pend) {
                int vv[16];
                #pragma unroll
                for (int k = 0; k < 16; k++) if (pend & (1u << k)) vv[k] = ldci(sp0 + k * strd);
                uint32_t np = 0;
                #pragma unroll
                for (int k = 0; k < 16; k++) if (pend & (1u << k)) {
                    if (vv[k] != -1) orig[k] = __int_as_float(vv[k]); else np |= 1u << k;
                }
                pend = np;
            }
        }
    }
    #pragma unroll
    for (int k = 0; k < 16; k++) u[k] = orig[k];

    if (cond) {
        int bs = 0;
        for (int it = 0; it < 10; it++) {
            xT[bs][wv][lane] = u[0];
            xB[bs][wv][lane] = u[15];
            __syncthreads();
            float ub = xB[bs][(wv + 3) & 3][lane];   // row r0-1 (periodic)
            float ut = xT[bs][(wv + 1) & 3][lane];   // row r0+16 (periodic)
            float nu[16];
            #pragma unroll
            for (int k = 0; k < 16; k++) {
                float up = (k == 0) ? ub : u[k - 1];
                float dn = (k == 15) ? ut : u[k + 1];
                float hsum = rot_a(u[k]) + rot_b(u[k]);
                nu[k] = u[k] + a * (up + dn - 2.0f * u[k]) + bc * (hsum - 2.0f * u[k]);
            }
            #pragma unroll
            for (int k = 0; k < 16; k++) u[k] = nu[k];
            bs ^= 1;
        }
        // blend
        #pragma unroll
        for (int k = 0; k < 16; k++) {
            int r = r0 + k;
            if (r < bh && lane < bw) {
                float byw = (y0 > 0 && r < 16) ? (float)r * (1.0f / 16.0f) : 1.0f;
                float bxw = (x0 > 0 && lane < 16) ? (float)lane * (1.0f / 16.0f) : 1.0f;
                float wgt = byw * bxw;
                u[k] = orig[k] * (1.0f - wgt) + u[k] * wgt;
            }
        }
    }

    // publish strips FIRST (sentinel-armed words self-announce; no drain/flag
    // on the chain), then the exclusive 48x48 core -> D
    #pragma unroll
    for (int k = 0; k < 16; k++) {
        int r = r0 + k;
        if (r < bh && lane < bw) {
            if (bw == 64 && lane >= 48) stc(RG + r * 16 + (lane - 48), u[k]);   // right strip (j<10)
            if (r >= 48)                stc(BG + (r - 48) * 64 + lane, u[k]);   // bottom strip (i<10)
        }
    }
    #pragma unroll
    for (int k = 0; k < 16; k++) {
        int r = r0 + k;
        if (r < 48 && r < bh && lane < 48 && lane < bw)
            stc(&Db[(y0 + r) * W + x0 + lane], u[k]);
    }
    asm volatile("s_waitcnt vmcnt(0)" ::: "memory");   // per-wave drain (for C gating)
    __syncthreads();                                   // all waves drained
    if (tid == 0) stci(&wflag[me], 1);

    // ===== C: diffusion, 8 stages x 8 iters =====
    const int cx = xb + lane;
    const int gxc = min(max(cx, 0), 511);
    float cvr[16], chr[16], chl[16];
    int gyA[16];
    #pragma unroll
    for (int k = 0; k < 16; k++) {
        int cy = yb + r0 + k;
        gyA[k] = min(max(cy, 0), 511);
        cvr[k] = cvT[(r0 + k) * 74 + lane];    // 0 outside valid by construction
        chr[k] = chT[(r0 + k) * 74 + lane];
        chl[k] = dirL ? sh_a(chr[k]) : sh_b(chr[k]);   // lane0 -> 0 (halo col)
    }
    const float cvm1 = (wv == 0) ? 0.0f : cvT[(r0 - 1) * 74 + lane];

    float* Tb0 = T0 + b * HW;
    float* Tb1 = T1 + b * HW;
    float* ypb = ypred + b * HW;
    const bool cok = (lane >= 8 && lane < 56 && xb + lane < 512);

    for (int t = 1; t <= 8; t++) {
        const float* src = (t == 1) ? Db : (((t - 1) & 1) ? Tb1 : Tb0);
        if (wv == 0) {
            bool need = false;
            const int* fp = wflag;
            int thr = 1;
            if (t == 1) {
                if (lane < 9) {                                   // 3x3 incl center
                    int di = lane / 3 - 1, dj = lane % 3 - 1;
                    int ni = i + di, nj = j + dj;
                    if (ni >= 0 && ni < NBLKS && nj >= 0 && nj < NBLKS) {
                        need = true;
                        fp = &wflag[b * 121 + ni * NBLKS + nj];
                    }
                }
            } else {
                thr = t - 1;
                if (lane < 9) {
                    int di = lane / 3 - 1, dj = lane % 3 - 1;
                    int ni = i + di, nj = j + dj;
                    if ((di | dj) != 0 && ni >= 0 && ni < NBLKS && nj >= 0 && nj < NBLKS) {
                        need = true;
                        fp = &dflag[(b * 121 + ni * NBLKS + nj) * 16];
                    }
                }
            }
            while (true) {
                int v = need ? ldci(fp) : 0x7fffffff;
                if (__ballot(v < thr) == 0) break;
                __builtin_amdgcn_s_sleep(8);
            }
        }
        __syncthreads();
        float uq[16];
        #pragma unroll
        for (int k = 0; k < 16; k++) uq[k] = ldc(&src[gyA[k] * W + gxc]);

        int bs = 0;
        for (int it = 0; it < 8; it++) {
            xT[bs][wv][lane] = uq[0];
            xB[bs][wv][lane] = uq[15];
            __syncthreads();
            float ub = (wv > 0) ? xB[bs][wv - 1][lane] : uq[0];
            float ut = (wv < 3) ? xT[bs][wv + 1][lane] : uq[15];
            float V[16];
            #pragma unroll
            for (int k = 0; k < 16; k++) {
                float up = (k == 0) ? ub : uq[k - 1];
                float dn = (k == 15) ? ut : uq[k + 1];
                float cup = (k == 0) ? cvm1 : cvr[k - 1];
                V[k] = uq[k] + LDIFF * cvr[k] * (dn - uq[k]) - LDIFF * cup * (uq[k] - up);
            }
            #pragma unroll
            for (int k = 0; k < 16; k++) {
                float rA = rot_a(V[k]);
                float rB = rot_b(V[k]);
                float lf = dirL ? rA : rB;
                float rt = dirL ? rB : rA;
                uq[k] = V[k] + LDIFF * chr[k] * (rt - V[k]) - LDIFF * chl[k] * (V[k] - lf);
            }
            bs ^= 1;
        }

        if (t < 8) {
            float* dst = (t & 1) ? Tb1 : Tb0;
            if (cok) {
                #pragma unroll
                for (int k = 0; k < 16; k++) {
                    int r = r0 + k;
                    if (r >= 8 && r < 56) {
                        int y = yb + r;
                        if (y < 512) stc(&dst[y * W + xb + lane], uq[k]);
                    }
                }
            }
            asm volatile("s_waitcnt vmcnt(0)" ::: "memory");
            __syncthreads();
            if (tid == 0) stci(&dflag[me * 16], t);
        } else {
            if (cok) {
                #pragma unroll
                for (int k = 0; k < 16; k++) {
                    int r = r0 + k;
                    if (r >= 8 && r < 56) {
                        int y = yb + r;
                        if (y < 512) ypb[y * W + xb + lane] = uq[k];
                    }
                }
            }
        }
    }
}

extern "C" void kernel_launch(void* const* d_in, const int* in_sizes, int n_in,
                              void* d_out, int out_size, void* d_ws, size_t ws_size,
                              hipStream_t stream) {
    const float* guide   = (const float*)d_in[0];
    const float* initial = (const float*)d_in[1];
    float* y_pred = (float*)d_out;
    float* cv = y_pred + N_D;          // output 1
    float* ch = cv + N_CV;             // output 2

    uint8_t* w = (uint8_t*)d_ws;
    int* sync_ = (int*)w;                                  // 64 KB flag area
    float* EDG = (float*)(w + 65536);                      // 242 * 8 KB strips (sentinel)
    float* D   = EDG + (size_t)NBT * 2048;                 // 2 MB final cores
    float* T0  = D + N_D;
    float* T1  = T0 + N_D;
    // total ws use: 64 KB + ~1.9 MB + 3 * 2 MB ~= 8 MB

    (void)hipMemsetAsync(sync_, 0, 65536, stream);
    (void)hipMemsetAsync(EDG, 0xFF, (size_t)NBT * 8192, stream);
    kall<<<dim3(121, NB), 256, 0, stream>>>(guide, initial, cv, ch, D, EDG, T0, T1, y_pred, sync_);
}

// Round 4
// 322.971 us; speedup vs baseline: 1.9368x; 1.1898x over previous
//
#include <hip/hip_runtime.h>
#include <stdint.h>

#define LDIFF 0.24f

constexpr int H = 512, W = 512, NB = 2;
constexpr int HW = H * W;              // 2^18
constexpr int N_D = NB * HW;           // 524288
constexpr int CVH = 511, CVW = 512;
constexpr int CHH = 512, CHW = 511;
constexpr int N_CV = NB * CVH * CVW;   // 523264
constexpr int NBLKS = 11;              // 11x11 blocks, step 48
constexpr int NBT = NB * 121;          // 242 workgroups <= 256 CUs -> co-resident

// LLC-coherent (cross-XCD) access: relaxed agent atomics = sc1 ops through the
// Infinity Cache. Validated R4-R9 (prior session) + R0 here.
__device__ inline float ldc(const float* p) {
    return __hip_atomic_load(p, __ATOMIC_RELAXED, __HIP_MEMORY_SCOPE_AGENT);
}
__device__ inline void stc(float* p, float v) {
    __hip_atomic_store(p, v, __ATOMIC_RELAXED, __HIP_MEMORY_SCOPE_AGENT);
}
__device__ inline int ldci(const int* p) {
    return __hip_atomic_load(p, __ATOMIC_RELAXED, __HIP_MEMORY_SCOPE_AGENT);
}
__device__ inline void stci(int* p, int v) {
    __hip_atomic_store(p, v, __ATOMIC_RELAXED, __HIP_MEMORY_SCOPE_AGENT);
}

// wave64 DPP rotate/shift by 1 (VALU pipe, zero LDS traffic). Direction probed
// at runtime (dirL); the wavefront stencil's use (lf+rt) is direction-agnostic.
__device__ inline float rot_a(float x) {
    return __int_as_float(__builtin_amdgcn_update_dpp(0, __float_as_int(x), 0x134, 0xf, 0xf, false));
}
__device__ inline float rot_b(float x) {
    return __int_as_float(__builtin_amdgcn_update_dpp(0, __float_as_int(x), 0x13c, 0xf, 0xf, false));
}
__device__ inline float sh_a(float x) {
    return __int_as_float(__builtin_amdgcn_update_dpp(0, __float_as_int(x), 0x130, 0xf, 0xf, true));
}
__device__ inline float sh_b(float x) {
    return __int_as_float(__builtin_amdgcn_update_dpp(0, __float_as_int(x), 0x138, 0xf, 0xf, true));
}

// One fused B sub-iteration: SRC -> DST over rows m in [LO, HI].
// nu = u + a*(up+dn-2u) + bc*(lf+rt-2u), periodic horizontally via DPP rotate.
#define BSTEP(SRC, DST, LO, HI)                                                   \
    _Pragma("unroll")                                                             \
    for (int m = (LO); m <= (HI); m++) {                                          \
        float hs = rot_a(SRC[m]) + rot_b(SRC[m]);                                 \
        DST[m] = SRC[m] + a * (SRC[m - 1] + SRC[m + 1] - 2.0f * SRC[m])           \
                        + bc * (hs - 2.0f * SRC[m]);                              \
    }

// One fused C sub-iteration (vertical flux then horizontal flux, per row).
#define CSTEP(SRC, DST, LO, HI)                                                   \
    _Pragma("unroll")                                                             \
    for (int m = (LO); m <= (HI); m++) {                                          \
        float Vm = SRC[m] + LDIFF * cve[m] * (SRC[m + 1] - SRC[m])                \
                          - LDIFF * cve[m - 1] * (SRC[m] - SRC[m - 1]);           \
        float rA = rot_a(Vm), rB = rot_b(Vm);                                     \
        float lf = dirL ? rA : rB, rt = dirL ? rB : rA;                           \
        DST[m] = Vm + LDIFF * che[m] * (rt - Vm) - LDIFF * chle[m] * (Vm - lf);   \
    }

// ======================= ONE kernel, zero global barriers =======================
//  Protocol/structure = R0 (verified fastest: 270us). Change vs R0: the B 10-iter
//  loop runs as 2 fused groups of 5 iterations (5-row halo exchange, ranges
//  shrink 24->16) and the C 8-iter stage loop as 2 fused groups of 4 (4-row
//  halo): barriers per B-step 10 -> 2, per C-stage 8 -> 2. Overlapped-tiling
//  induction keeps center rows bit-exact; edge contamination stays outside the
//  stored core exactly as in the unfused version.
__global__ __launch_bounds__(256) void kall(
    const float* __restrict__ guide, const float* __restrict__ initial,
    float* __restrict__ cv, float* __restrict__ ch,
    float* __restrict__ D, float* __restrict__ T0, float* __restrict__ T1,
    float* __restrict__ ypred, int* __restrict__ sync_)
{
    __shared__ float cvT[73 * 74];
    __shared__ float chT[73 * 74];
    __shared__ float xT[2][4][5][64];   // group-published top rows (u[0..4])
    __shared__ float xB[2][4][5][64];   // group-published bottom rows (u[11..15])
    __shared__ float red[12];
    __shared__ float prmS[3];

    int* wflag = sync_;                   // (b*121+blk)*64 + wave*16
    int* dflag = sync_ + 16384;           // (b*121+blk)*16

    const int blk = blockIdx.x;           // 0..120
    const int i = blk / NBLKS, j = blk % NBLKS;
    const int b = blockIdx.y;
    const int tid = threadIdx.x;
    const int lane = tid & 63, wv = tid >> 6;
    const int r0 = wv * 16;
    const int me = b * 121 + blk;

    const int y0 = i * 48, x0 = j * 48;
    const int y1 = min(y0 + 64, 512), x1 = min(x0 + 64, 512);
    const int bh = y1 - y0, bw = x1 - x0;
    const int yb = y0 - 8, xb = x0 - 8;
    const float kinv = 1.0f / (0.03f * 0.03f);

    // ===== A1: local cv/ch (rows yb..yb+72, cols xb..xb+72; 0 outside valid) =====
    const float* gb = guide + (size_t)b * 3 * HW;
    for (int p = tid; p < 73 * 73; p += 256) {
        int rr = p / 73, cc2 = p - rr * 73;
        int y = yb + rr, x = xb + cc2;
        float cvv = 0.0f, chv = 0.0f;
        if (y >= 0 && y < 512 && x >= 0 && x < 512) {
            const float* g = gb + y * W + x;
            float g0 = g[0], g1 = g[HW], g2 = g[2 * HW];
            if (y < 511) {
                float d = (fabsf(g[W] - g0) + fabsf(g[HW + W] - g1) + fabsf(g[2 * HW + W] - g2)) * (1.0f / 3.0f);
                cvv = 1.0f / (1.0f + d * d * kinv);
            }
            if (x < 511) {
                float d = (fabsf(g[1] - g0) + fabsf(g[HW + 1] - g1) + fabsf(g[2 * HW + 1] - g2)) * (1.0f / 3.0f);
                chv = 1.0f / (1.0f + d * d * kinv);
            }
        }
        cvT[rr * 74 + cc2] = cvv;
        chT[rr * 74 + cc2] = chv;
    }
    __syncthreads();

    // ===== A2: write disjoint cv/ch output partitions (48x48 cores) =====
    {
        int rcv = min(y0 + 48, CVH) - y0, ccv = min(x0 + 48, CVW) - x0;
        float* cvo = cv + b * CVH * CVW;
        for (int p = tid; p < rcv * ccv; p += 256) {
            int r = p / ccv, c = p - r * ccv;
            cvo[(y0 + r) * CVW + x0 + c] = cvT[(r + 8) * 74 + c + 8];
        }
        int rch = min(y0 + 48, CHH) - y0, cch = min(x0 + 48, CHW) - x0;
        float* cho = ch + b * CHH * CHW;
        for (int p = tid; p < rch * cch; p += 256) {
            int r = p / cch, c = p - r * cch;
            cho[(y0 + r) * CHW + x0 + c] = chT[(r + 8) * 74 + c + 8];
        }
    }

    // ===== A3: params — wave butterfly + 1 barrier =====
    float scv = 0.f, sch = 0.f, sun = 0.f;
    {
        int n = (bh - 1) * bw;
        for (int p = tid; p < n; p += 256) { int r = p / bw, c = p - r * bw; scv += cvT[(r + 8) * 74 + c + 8]; }
    }
    {
        int cols = bw - 1, n = bh * cols;
        for (int p = tid; p < n; p += 256) { int r = p / cols, c = p - r * cols; sch += chT[(r + 8) * 74 + c + 8]; }
    }
    const int ur = min(y1, 511) - y0, uc = min(x1, 511) - x0;
    {
        int n = ur * uc;
        for (int p = tid; p < n; p += 256) {
            int r = p / uc, c = p - r * uc;
            float s1 = 0.f, s2 = 0.f, t1 = 0.f, t2 = 0.f;
            #pragma unroll
            for (int dy = 0; dy < 3; dy++)
                #pragma unroll
                for (int dx = 0; dx < 3; dx++) {
                    float v = cvT[(r + 7 + dy) * 74 + c + 7 + dx]; s1 += v; s2 += v * v;
                    float w2 = chT[(r + 7 + dy) * 74 + c + 7 + dx]; t1 += w2; t2 += w2 * w2;
                }
            float m = s1 * (1.0f / 9.0f);
            float vcv = s2 * (1.0f / 9.0f) - m * m;
            m = t1 * (1.0f / 9.0f);
            float vch = t2 * (1.0f / 9.0f) - m * m;
            if (vcv < 0.1f && vch < 0.1f) sun += 1.f;
        }
    }
    #pragma unroll
    for (int m = 1; m < 64; m <<= 1) {
        scv += __shfl_xor(scv, m);
        sch += __shfl_xor(sch, m);
        sun += __shfl_xor(sun, m);
    }
    if (lane == 0) { red[wv * 3] = scv; red[wv * 3 + 1] = sch; red[wv * 3 + 2] = sun; }
    __syncthreads();
    if (tid == 0) {
        float a0 = red[0] + red[3] + red[6] + red[9];
        float a1 = red[1] + red[4] + red[7] + red[10];
        float a2 = red[2] + red[5] + red[8] + red[11];
        prmS[0] = a0 / (float)((bh - 1) * bw);
        prmS[1] = a1 / (float)(bh * (bw - 1));
        prmS[2] = (a2 / (float)(ur * uc) > 0.7f) ? 1.0f : 0.0f;
    }
    __syncthreads();

    // DPP direction probe (wave-uniform)
    int prb = __builtin_amdgcn_update_dpp(0, lane, 0x134, 0xf, 0xf, false);
    const bool dirL = (prb == ((lane + 63) & 63));

    const bool cond = prmS[2] > 0.5f;
    const float a = LDIFF * prmS[0], bc = LDIFF * prmS[1];
    float* Db = D + b * HW;
    const float* ini = initial + b * HW;

    // ===== B: wavefront (R0 protocol; fused 2x5 iteration groups) =====
    const int mh = bh - 1, mw = bw - 1;
    const int ccw = lane & mw;

    if (!cond) {
        // region unchanged: write my non-strip region from `initial`
        #pragma unroll
        for (int k = 0; k < 16; k++) {
            int r = r0 + k;
            if (r < bh && (i == 0 || r >= 16) && lane < bw && (j == 0 || lane >= 16)) {
                int ad = (y0 + r) * W + x0 + lane;
                stc(&Db[ad], ini[ad]);
            }
        }
        asm volatile("s_waitcnt vmcnt(0)" ::: "memory");
        if (lane == 0) stci(&wflag[me * 64 + wv * 16], 1);
    } else {
        float u[16], orig[16];
        int addr[16]; bool fD[16];
        #pragma unroll
        for (int k = 0; k < 16; k++) {
            int rr = (r0 + k) & mh;
            addr[k] = (y0 + rr) * W + x0 + ccw;
            fD[k] = (i > 0 && rr < 16) || (j > 0 && ccw < 16);
            if (!fD[k]) orig[k] = ini[addr[k]];     // prefetch interior pre-wait
        }
        // ---- ballot poll: 6 dep sub-flags, one load instr per iteration ----
        if (wv == 0) {
            bool need = false;
            const int* fp = &wflag[me * 64];
            if (lane < 3) {
                if (j > 0) { need = true; fp = &wflag[(b * 121 + i * NBLKS + j - 1) * 64 + (lane + 1) * 16]; }
            } else if (lane == 3) {
                if (i > 0) { need = true; fp = &wflag[(b * 121 + (i - 1) * NBLKS + j) * 64 + 3 * 16]; }
            } else if (lane == 4) {
                if (i > 0 && j < 10) { need = true; fp = &wflag[(b * 121 + (i - 1) * NBLKS + j + 1) * 64 + 3 * 16]; }
            } else if (lane == 5) {
                if (i > 0 && j > 0) { need = true; fp = &wflag[(b * 121 + (i - 1) * NBLKS + j - 1) * 64 + 3 * 16]; }
            }
            while (true) {
                int v = need ? ldci(fp) : 1;
                if (__ballot(v == 0) == 0) break;
                __builtin_amdgcn_s_sleep(0);
            }
        }
        __syncthreads();
        #pragma unroll
        for (int k = 0; k < 16; k++) if (fD[k]) orig[k] = ldc(&Db[addr[k]]);
        #pragma unroll
        for (int k = 0; k < 16; k++) u[k] = orig[k];

        // ---- 10 iterations as 2 fused groups of 5 (5-row periodic halo) ----
        // w index m: row r0 + m - 5 (periodic via wave ring). Center m=5..20.
        float wa[26], wb[26];
        #pragma unroll
        for (int g = 0; g < 2; ++g) {
            #pragma unroll
            for (int q = 0; q < 5; q++) {
                xT[g][wv][q][lane] = u[q];          // rows r0..r0+4
                xB[g][wv][q][lane] = u[11 + q];     // rows r0+11..r0+15
            }
            __syncthreads();
            #pragma unroll
            for (int q = 0; q < 5; q++) {
                wa[q]      = xB[g][(wv + 3) & 3][q][lane];   // rows r0-5..r0-1
                wa[21 + q] = xT[g][(wv + 1) & 3][q][lane];   // rows r0+16..r0+20
            }
            #pragma unroll
            for (int q = 0; q < 16; q++) wa[5 + q] = u[q];
            BSTEP(wa, wb, 1, 24);
            BSTEP(wb, wa, 2, 23);
            BSTEP(wa, wb, 3, 22);
            BSTEP(wb, wa, 4, 21);
            BSTEP(wa, wb, 5, 20);
            #pragma unroll
            for (int q = 0; q < 16; q++) u[q] = wb[5 + q];
        }

        #pragma unroll
        for (int k = 0; k < 16; k++) {
            int r = r0 + k;
            if (r < bh && lane < bw) {
                float byw = (y0 > 0 && r < 16) ? (float)r * (1.0f / 16.0f) : 1.0f;
                float bxw = (x0 > 0 && lane < 16) ? (float)lane * (1.0f / 16.0f) : 1.0f;
                float wgt = byw * bxw;
                stc(&Db[(y0 + r) * W + x0 + lane], orig[k] * (1.0f - wgt) + u[k] * wgt);
            }
        }
        asm volatile("s_waitcnt vmcnt(0)" ::: "memory");   // per-wave drain of own stores
        if (lane == 0) stci(&wflag[me * 64 + wv * 16], 1); // per-wave publish
    }
    __syncthreads();   // all waves published; own D region complete for phase C

    // ===== C: diffusion, 8 stages x (2 fused groups of 4 iters) =====
    const int cx = xb + lane;
    const int gxc = min(max(cx, 0), 511);
    int gyA[16];
    #pragma unroll
    for (int k = 0; k < 16; k++) {
        int cy = yb + r0 + k;
        gyA[k] = min(max(cy, 0), 511);
    }
    // extended coefficient cache: row r0 + m - 4 for m=0..23 (0 out of range)
    float cve[24], che[24], chle[24];
    #pragma unroll
    for (int m = 0; m < 24; m++) {
        int rr = r0 + m - 4;                 // max 48+19 = 67 < 73
        bool ok = (rr >= 0);
        cve[m] = ok ? cvT[rr * 74 + lane] : 0.0f;
        che[m] = ok ? chT[rr * 74 + lane] : 0.0f;
        chle[m] = dirL ? sh_a(che[m]) : sh_b(che[m]);   // lane0 -> 0 (halo col)
    }

    float* Tb0 = T0 + b * HW;
    float* Tb1 = T1 + b * HW;
    float* ypb = ypred + b * HW;
    const bool cok = (lane >= 8 && lane < 56 && xb + lane < 512);

    for (int t = 1; t <= 8; t++) {
        if (wv == 0) {
            bool need = false;
            const int* fp = &wflag[me * 64];
            int thr = 1;
            if (t == 1) {
                if (lane < 36) {
                    int nb = lane >> 2;
                    int di = nb / 3 - 1, dj = nb % 3 - 1;
                    int ni = i + di, nj = j + dj;
                    if ((di | dj) != 0 && ni >= 0 && ni < NBLKS && nj >= 0 && nj < NBLKS) {
                        need = true;
                        fp = &wflag[(b * 121 + ni * NBLKS + nj) * 64 + (lane & 3) * 16];
                    }
                }
            } else {
                thr = t - 1;
                if (lane < 9) {
                    int di = lane / 3 - 1, dj = lane % 3 - 1;
                    int ni = i + di, nj = j + dj;
                    if ((di | dj) != 0 && ni >= 0 && ni < NBLKS && nj >= 0 && nj < NBLKS) {
                        need = true;
                        fp = &dflag[(b * 121 + ni * NBLKS + nj) * 16];
                    }
                }
            }
            while (true) {
                int v = need ? ldci(fp) : 0x7fffffff;
                if (__ballot(v < thr) == 0) break;
                __builtin_amdgcn_s_sleep(8);
            }
        }
        __syncthreads();
        const float* src = (t == 1) ? Db : (((t - 1) & 1) ? Tb1 : Tb0);
        float u[16];
        #pragma unroll
        for (int k = 0; k < 16; k++) u[k] = ldc(&src[gyA[k] * W + gxc]);

        // ---- 8 iterations as 2 fused groups of 4 (4-row halo) ----
        // w index m: row r0 + m - 4. Center m=4..19.
        #pragma unroll
        for (int g = 0; g < 2; ++g) {
            #pragma unroll
            for (int q = 0; q < 4; q++) {
                xT[g][wv][q][lane] = u[q];          // rows r0..r0+3
                xB[g][wv][q][lane] = u[12 + q];     // rows r0+12..r0+15
            }
            __syncthreads();
            float wa[24], wb[24];
            #pragma unroll
            for (int q = 0; q < 4; q++) {
                wa[q]      = (wv > 0) ? xB[g][wv - 1][q][lane] : u[0];    // rows r0-4..r0-1
                wa[20 + q] = (wv < 3) ? xT[g][wv + 1][q][lane] : u[15];   // rows r0+16..r0+19
            }
            #pragma unroll
            for (int q = 0; q < 16; q++) wa[4 + q] = u[q];
            CSTEP(wa, wb, 1, 22);
            CSTEP(wb, wa, 2, 21);
            CSTEP(wa, wb, 3, 20);
            CSTEP(wb, wa, 4, 19);
            #pragma unroll
            for (int q = 0; q < 16; q++) u[q] = wa[4 + q];
        }

        if (t < 8) {
            float* dst = (t & 1) ? Tb1 : Tb0;
            if (cok) {
                #pragma unroll
                for (int k = 0; k < 16; k++) {
                    int r = r0 + k;
                    if (r >= 8 && r < 56) {
                        int y = yb + r;
                        if (y < 512) stc(&dst[y * W + xb + lane], u[k]);
                    }
                }
            }
            asm volatile("s_waitcnt vmcnt(0)" ::: "memory");
            __syncthreads();
            if (tid == 0) stci(&dflag[me * 16], t);
        } else {
            if (cok) {
                #pragma unroll
                for (int k = 0; k < 16; k++) {
                    int r = r0 + k;
                    if (r >= 8 && r < 56) {
                        int y = yb + r;
                        if (y < 512) ypb[y * W + xb + lane] = u[k];
                    }
                }
            }
        }
    }
}

extern "C" void kernel_launch(void* const* d_in, const int* in_sizes, int n_in,
                              void* d_out, int out_size, void* d_ws, size_t ws_size,
                              hipStream_t stream) {
    const float* guide   = (const float*)d_in[0];
    const float* initial = (const float*)d_in[1];
    float* y_pred = (float*)d_out;
    float* cv = y_pred + N_D;          // output 1
    float* ch = cv + N_CV;             // output 2

    uint8_t* w = (uint8_t*)d_ws;
    int* sync_ = (int*)w;              // wflag @0 (242*64 ints), dflag @16384 ints
    float* D  = (float*)(w + 131072);
    float* T0 = (float*)(w + 131072 + (size_t)N_D * 4);
    float* T1 = (float*)(w + 131072 + (size_t)2 * N_D * 4);

    (void)hipMemsetAsync(sync_, 0, 131072, stream);
    kall<<<dim3(121, NB), 256, 0, stream>>>(guide, initial, cv, ch, D, T0, T1, y_pred, sync_);
}

// Round 5
// 307.006 us; speedup vs baseline: 2.0375x; 1.0520x over previous
//
#include <hip/hip_runtime.h>
#include <stdint.h>

#define LDIFF 0.24f

constexpr int H = 512, W = 512, NB = 2;
constexpr int HW = H * W;              // 2^18
constexpr int N_D = NB * HW;           // 524288
constexpr int CVH = 511, CVW = 512;
constexpr int CHH = 512, CHW = 511;
constexpr int N_CV = NB * CVH * CVW;   // 523264
constexpr int NBLKS = 11;              // 11x11 blocks, step 48
constexpr int NBT = NB * 121;          // 242 workgroups <= 256 CUs -> co-resident

// LLC-coherent (cross-XCD) access: relaxed agent atomics = sc1 ops through the
// Infinity Cache. Validated R4-R9 (prior session) + R0 here.
__device__ inline float ldc(const float* p) {
    return __hip_atomic_load(p, __ATOMIC_RELAXED, __HIP_MEMORY_SCOPE_AGENT);
}
__device__ inline void stc(float* p, float v) {
    __hip_atomic_store(p, v, __ATOMIC_RELAXED, __HIP_MEMORY_SCOPE_AGENT);
}
__device__ inline int ldci(const int* p) {
    return __hip_atomic_load(p, __ATOMIC_RELAXED, __HIP_MEMORY_SCOPE_AGENT);
}
__device__ inline void stci(int* p, int v) {
    __hip_atomic_store(p, v, __ATOMIC_RELAXED, __HIP_MEMORY_SCOPE_AGENT);
}

// wave64 DPP rotate/shift by 1 (VALU pipe, zero LDS traffic). Direction probed
// at runtime (dirL); the wavefront stencil's use (lf+rt) is direction-agnostic.
__device__ inline float rot_a(float x) {
    return __int_as_float(__builtin_amdgcn_update_dpp(0, __float_as_int(x), 0x134, 0xf, 0xf, false));
}
__device__ inline float rot_b(float x) {
    return __int_as_float(__builtin_amdgcn_update_dpp(0, __float_as_int(x), 0x13c, 0xf, 0xf, false));
}
__device__ inline float sh_a(float x) {
    return __int_as_float(__builtin_amdgcn_update_dpp(0, __float_as_int(x), 0x130, 0xf, 0xf, true));
}
__device__ inline float sh_b(float x) {
    return __int_as_float(__builtin_amdgcn_update_dpp(0, __float_as_int(x), 0x138, 0xf, 0xf, true));
}

// One fused B sub-iteration: SRC -> DST over rows m in [LO, HI].
#define BSTEP(SRC, DST, LO, HI)                                                   \
    _Pragma("unroll")                                                             \
    for (int m = (LO); m <= (HI); m++) {                                          \
        float hs = rot_a(SRC[m]) + rot_b(SRC[m]);                                 \
        DST[m] = SRC[m] + a * (SRC[m - 1] + SRC[m + 1] - 2.0f * SRC[m])           \
                        + bc * (hs - 2.0f * SRC[m]);                              \
    }

// One fused C sub-iteration (vertical flux then horizontal flux, per row).
#define CSTEP(SRC, DST, LO, HI)                                                   \
    _Pragma("unroll")                                                             \
    for (int m = (LO); m <= (HI); m++) {                                          \
        float Vm = SRC[m] + LDIFF * cve[m] * (SRC[m + 1] - SRC[m])                \
                          - LDIFF * cve[m - 1] * (SRC[m] - SRC[m - 1]);           \
        float rA = rot_a(Vm), rB = rot_b(Vm);                                     \
        float lf = dirL ? rA : rB, rt = dirL ? rB : rA;                           \
        DST[m] = Vm + LDIFF * che[m] * (rt - Vm) - LDIFF * chle[m] * (Vm - lf);   \
    }

// ======================= ONE kernel, zero global barriers =======================
//  Protocol = R0/R4 (proven). R5 cuts chain payloads:
//  B) split-publish: outgoing strips stored + per-wave drained + flagA FIRST
//     (chain drain ~8KB not 64KB); interior + flagB (gates C t=1) off-chain.
//     Per-wave dep polls (L.w[row/16] strip flag; top-row waves add U/UR/UL.w3)
//     with no post-poll block barrier — fixes R0's L.w0 corner race too.
//  C) register-carry: own-core cells persist in u[] across stages (halo-only
//     reloads, 4096->1792 cells); stages 1-7 store only the core's outer
//     8-ring (all neighbors ever read), 2304->~1280 cells.
__global__ __launch_bounds__(256) void kall(
    const float* __restrict__ guide, const float* __restrict__ initial,
    float* __restrict__ cv, float* __restrict__ ch,
    float* __restrict__ D, float* __restrict__ T0, float* __restrict__ T1,
    float* __restrict__ ypred, int* __restrict__ sync_)
{
    __shared__ float cvT[73 * 74];
    __shared__ float chT[73 * 74];
    __shared__ float xT[2][4][5][64];   // group-published top rows
    __shared__ float xB[2][4][5][64];   // group-published bottom rows
    __shared__ float red[12];
    __shared__ float prmS[3];

    int* wflag = sync_;                   // (me)*64 + wv*16 (+0 strip, +8 full)
    int* dflag = sync_ + 16384;           // (me)*16

    const int blk = blockIdx.x;           // 0..120
    const int i = blk / NBLKS, j = blk % NBLKS;
    const int b = blockIdx.y;
    const int tid = threadIdx.x;
    const int lane = tid & 63, wv = tid >> 6;
    const int r0 = wv * 16;
    const int me = b * 121 + blk;

    const int y0 = i * 48, x0 = j * 48;
    const int y1 = min(y0 + 64, 512), x1 = min(x0 + 64, 512);
    const int bh = y1 - y0, bw = x1 - x0;
    const int yb = y0 - 8, xb = x0 - 8;
    const float kinv = 1.0f / (0.03f * 0.03f);

    // ===== A1: local cv/ch (rows yb..yb+72, cols xb..xb+72; 0 outside valid) =====
    const float* gb = guide + (size_t)b * 3 * HW;
    for (int p = tid; p < 73 * 73; p += 256) {
        int rr = p / 73, cc2 = p - rr * 73;
        int y = yb + rr, x = xb + cc2;
        float cvv = 0.0f, chv = 0.0f;
        if (y >= 0 && y < 512 && x >= 0 && x < 512) {
            const float* g = gb + y * W + x;
            float g0 = g[0], g1 = g[HW], g2 = g[2 * HW];
            if (y < 511) {
                float d = (fabsf(g[W] - g0) + fabsf(g[HW + W] - g1) + fabsf(g[2 * HW + W] - g2)) * (1.0f / 3.0f);
                cvv = 1.0f / (1.0f + d * d * kinv);
            }
            if (x < 511) {
                float d = (fabsf(g[1] - g0) + fabsf(g[HW + 1] - g1) + fabsf(g[2 * HW + 1] - g2)) * (1.0f / 3.0f);
                chv = 1.0f / (1.0f + d * d * kinv);
            }
        }
        cvT[rr * 74 + cc2] = cvv;
        chT[rr * 74 + cc2] = chv;
    }
    __syncthreads();

    // ===== A2: write disjoint cv/ch output partitions (48x48 cores) =====
    {
        int rcv = min(y0 + 48, CVH) - y0, ccv = min(x0 + 48, CVW) - x0;
        float* cvo = cv + b * CVH * CVW;
        for (int p = tid; p < rcv * ccv; p += 256) {
            int r = p / ccv, c = p - r * ccv;
            cvo[(y0 + r) * CVW + x0 + c] = cvT[(r + 8) * 74 + c + 8];
        }
        int rch = min(y0 + 48, CHH) - y0, cch = min(x0 + 48, CHW) - x0;
        float* cho = ch + b * CHH * CHW;
        for (int p = tid; p < rch * cch; p += 256) {
            int r = p / cch, c = p - r * cch;
            cho[(y0 + r) * CHW + x0 + c] = chT[(r + 8) * 74 + c + 8];
        }
    }

    // ===== A3: params — wave butterfly + 1 barrier =====
    float scv = 0.f, sch = 0.f, sun = 0.f;
    {
        int n = (bh - 1) * bw;
        for (int p = tid; p < n; p += 256) { int r = p / bw, c = p - r * bw; scv += cvT[(r + 8) * 74 + c + 8]; }
    }
    {
        int cols = bw - 1, n = bh * cols;
        for (int p = tid; p < n; p += 256) { int r = p / cols, c = p - r * cols; sch += chT[(r + 8) * 74 + c + 8]; }
    }
    const int ur = min(y1, 511) - y0, uc = min(x1, 511) - x0;
    {
        int n = ur * uc;
        for (int p = tid; p < n; p += 256) {
            int r = p / uc, c = p - r * uc;
            float s1 = 0.f, s2 = 0.f, t1 = 0.f, t2 = 0.f;
            #pragma unroll
            for (int dy = 0; dy < 3; dy++)
                #pragma unroll
                for (int dx = 0; dx < 3; dx++) {
                    float v = cvT[(r + 7 + dy) * 74 + c + 7 + dx]; s1 += v; s2 += v * v;
                    float w2 = chT[(r + 7 + dy) * 74 + c + 7 + dx]; t1 += w2; t2 += w2 * w2;
                }
            float m = s1 * (1.0f / 9.0f);
            float vcv = s2 * (1.0f / 9.0f) - m * m;
            m = t1 * (1.0f / 9.0f);
            float vch = t2 * (1.0f / 9.0f) - m * m;
            if (vcv < 0.1f && vch < 0.1f) sun += 1.f;
        }
    }
    #pragma unroll
    for (int m = 1; m < 64; m <<= 1) {
        scv += __shfl_xor(scv, m);
        sch += __shfl_xor(sch, m);
        sun += __shfl_xor(sun, m);
    }
    if (lane == 0) { red[wv * 3] = scv; red[wv * 3 + 1] = sch; red[wv * 3 + 2] = sun; }
    __syncthreads();
    if (tid == 0) {
        float a0 = red[0] + red[3] + red[6] + red[9];
        float a1 = red[1] + red[4] + red[7] + red[10];
        float a2 = red[2] + red[5] + red[8] + red[11];
        prmS[0] = a0 / (float)((bh - 1) * bw);
        prmS[1] = a1 / (float)(bh * (bw - 1));
        prmS[2] = (a2 / (float)(ur * uc) > 0.7f) ? 1.0f : 0.0f;
    }
    __syncthreads();

    // DPP direction probe (wave-uniform)
    int prb = __builtin_amdgcn_update_dpp(0, lane, 0x134, 0xf, 0xf, false);
    const bool dirL = (prb == ((lane + 63) & 63));

    const bool cond = prmS[2] > 0.5f;
    const float a = LDIFF * prmS[0], bc = LDIFF * prmS[1];
    float* Db = D + b * HW;
    const float* ini = initial + b * HW;

    // ===== B: wavefront (split-publish, per-wave deps, fused 2x5 groups) =====
    const int mh = bh - 1, mw = bw - 1;
    const int ccw = lane & mw;

    if (!cond) {
        // region unchanged: write my non-strip region from `initial`
        #pragma unroll
        for (int k = 0; k < 16; k++) {
            int r = r0 + k;
            if (r < bh && (i == 0 || r >= 16) && lane < bw && (j == 0 || lane >= 16)) {
                int ad = (y0 + r) * W + x0 + lane;
                stc(&Db[ad], ini[ad]);
            }
        }
        asm volatile("s_waitcnt vmcnt(0)" ::: "memory");
        if (lane == 0) {
            stci(&wflag[me * 64 + wv * 16], 1);       // strip flag
            stci(&wflag[me * 64 + wv * 16 + 8], 1);   // full flag
        }
    } else {
        float u[16], orig[16];
        int addr[16]; bool fD[16];
        #pragma unroll
        for (int k = 0; k < 16; k++) {
            int rr = (r0 + k) & mh;
            addr[k] = (y0 + rr) * W + x0 + ccw;
            fD[k] = (i > 0 && rr < 16) || (j > 0 && ccw < 16);
            if (!fD[k]) orig[k] = ini[addr[k]];     // prefetch interior pre-wait
        }
        // ---- per-wave dep poll on STRIP flags (row-matched; no block barrier) ----
        {
            const int Lw = (r0 & mh) >> 4;                    // L wave covering my rows
            const bool needU = (i > 0) && ((r0 & mh) < 16);   // my rows include 0..15
            bool need = false;
            const int* fp = &wflag[me * 64];
            if (lane == 0) {
                if (j > 0) { need = true; fp = &wflag[(me - 1) * 64 + Lw * 16]; }
            } else if (lane == 1) {
                if (needU) { need = true; fp = &wflag[(me - NBLKS) * 64 + 3 * 16]; }
            } else if (lane == 2) {
                if (needU && j < 10) { need = true; fp = &wflag[(me - NBLKS + 1) * 64 + 3 * 16]; }
            } else if (lane == 3) {
                if (needU && j > 0) { need = true; fp = &wflag[(me - NBLKS - 1) * 64 + 3 * 16]; }
            }
            while (true) {
                int v = need ? ldci(fp) : 1;
                if (__ballot(v == 0) == 0) break;
                __builtin_amdgcn_s_sleep(0);
            }
        }
        #pragma unroll
        for (int k = 0; k < 16; k++) if (fD[k]) orig[k] = ldc(&Db[addr[k]]);
        #pragma unroll
        for (int k = 0; k < 16; k++) u[k] = orig[k];

        // ---- 10 iterations as 2 fused groups of 5 (5-row periodic halo) ----
        float wa[26], wb[26];
        #pragma unroll
        for (int g = 0; g < 2; ++g) {
            #pragma unroll
            for (int q = 0; q < 5; q++) {
                xT[g][wv][q][lane] = u[q];          // rows r0..r0+4
                xB[g][wv][q][lane] = u[11 + q];     // rows r0+11..r0+15
            }
            __syncthreads();
            #pragma unroll
            for (int q = 0; q < 5; q++) {
                wa[q]      = xB[g][(wv + 3) & 3][q][lane];   // rows r0-5..r0-1
                wa[21 + q] = xT[g][(wv + 1) & 3][q][lane];   // rows r0+16..r0+20
            }
            #pragma unroll
            for (int q = 0; q < 16; q++) wa[5 + q] = u[q];
            BSTEP(wa, wb, 1, 24);
            BSTEP(wb, wa, 2, 23);
            BSTEP(wa, wb, 3, 22);
            BSTEP(wb, wa, 4, 21);
            BSTEP(wa, wb, 5, 20);
            #pragma unroll
            for (int q = 0; q < 16; q++) u[q] = wb[5 + q];
        }

        // blend into final values
        #pragma unroll
        for (int k = 0; k < 16; k++) {
            int r = r0 + k;
            float byw = (y0 > 0 && r < 16) ? (float)r * (1.0f / 16.0f) : 1.0f;
            float bxw = (x0 > 0 && lane < 16) ? (float)lane * (1.0f / 16.0f) : 1.0f;
            float wgt = byw * bxw;
            u[k] = orig[k] * (1.0f - wgt) + u[k] * wgt;
        }
        // 1) outgoing strips (right 16-col if j<10; bottom 16-row) -> tiny drain -> flagA
        #pragma unroll
        for (int k = 0; k < 16; k++) {
            int r = r0 + k;
            bool in = (r < bh && lane < bw);
            bool sc = (bw == 64 && lane >= 48) || (r >= 48);
            if (in && sc) stc(&Db[(y0 + r) * W + x0 + lane], u[k]);
        }
        asm volatile("s_waitcnt vmcnt(0)" ::: "memory");
        if (lane == 0) stci(&wflag[me * 64 + wv * 16], 1);       // strip flag (chain)
        // 2) interior -> drain -> flagB (gates C t=1 only)
        #pragma unroll
        for (int k = 0; k < 16; k++) {
            int r = r0 + k;
            bool in = (r < bh && lane < bw);
            bool sc = (bw == 64 && lane >= 48) || (r >= 48);
            if (in && !sc) stc(&Db[(y0 + r) * W + x0 + lane], u[k]);
        }
        asm volatile("s_waitcnt vmcnt(0)" ::: "memory");
        if (lane == 0) stci(&wflag[me * 64 + wv * 16 + 8], 1);   // full flag
    }
    __syncthreads();   // all waves published; own D region complete for phase C

    // ===== C: diffusion, 8 stages x (2 fused groups of 4), reg-carry + ring-store =====
    const int cx = xb + lane;
    const int gxc = min(max(cx, 0), 511);
    int gyA[16];
    #pragma unroll
    for (int k = 0; k < 16; k++) {
        int cy = yb + r0 + k;
        gyA[k] = min(max(cy, 0), 511);
    }
    // extended coefficient cache: row r0 + m - 4 for m=0..23 (0 out of range)
    float cve[24], che[24], chle[24];
    #pragma unroll
    for (int m = 0; m < 24; m++) {
        int rr = r0 + m - 4;                 // max 48+19 = 67 < 73
        bool ok = (rr >= 0);
        cve[m] = ok ? cvT[rr * 74 + lane] : 0.0f;
        che[m] = ok ? chT[rr * 74 + lane] : 0.0f;
        chle[m] = dirL ? sh_a(che[m]) : sh_b(che[m]);   // lane0 -> 0 (halo col)
    }

    float* Tb0 = T0 + b * HW;
    float* Tb1 = T1 + b * HW;
    float* ypb = ypred + b * HW;

    // own-core / ring classification. Core = 48x48 (or clipped) tile exactly
    // tiling the image; window rows/cols 8.. map to core rows/cols 0..
    const int coreh = min(48, 512 - y0), corew = min(48, 512 - x0);
    const bool laneC = (lane >= 8) && (lane < 8 + corew);
    bool ownc[16], ringk[16];
    #pragma unroll
    for (int k = 0; k < 16; k++) {
        int wr = r0 + k;
        ownc[k] = laneC && (wr >= 8) && (wr < 8 + coreh);
        int cr = wr - 8, cl = lane - 8;
        ringk[k] = ownc[k] && (cr < 8 || cr >= coreh - 8 || cl < 8 || cl >= corew - 8);
    }

    float u[16];
    for (int t = 1; t <= 8; t++) {
        if (wv == 0) {
            bool need = false;
            const int* fp = &wflag[me * 64];
            int thr = 1;
            if (t == 1) {
                if (lane < 36) {
                    int nb = lane >> 2;
                    int di = nb / 3 - 1, dj = nb % 3 - 1;
                    int ni = i + di, nj = j + dj;
                    if ((di | dj) != 0 && ni >= 0 && ni < NBLKS && nj >= 0 && nj < NBLKS) {
                        need = true;
                        fp = &wflag[(b * 121 + ni * NBLKS + nj) * 64 + (lane & 3) * 16 + 8];  // FULL flags
                    }
                }
            } else {
                thr = t - 1;
                if (lane < 9) {
                    int di = lane / 3 - 1, dj = lane % 3 - 1;
                    int ni = i + di, nj = j + dj;
                    if ((di | dj) != 0 && ni >= 0 && ni < NBLKS && nj >= 0 && nj < NBLKS) {
                        need = true;
                        fp = &dflag[(b * 121 + ni * NBLKS + nj) * 16];
                    }
                }
            }
            while (true) {
                int v = need ? ldci(fp) : 0x7fffffff;
                if (__ballot(v < thr) == 0) break;
                __builtin_amdgcn_s_sleep(8);
            }
        }
        __syncthreads();
        const float* src = (t == 1) ? Db : (((t - 1) & 1) ? Tb1 : Tb0);
        if (t == 1) {
            #pragma unroll
            for (int k = 0; k < 16; k++) u[k] = ldc(&src[gyA[k] * W + gxc]);
        } else {
            // reg-carry: own-core cells already in u[]; reload only halo cells
            #pragma unroll
            for (int k = 0; k < 16; k++) if (!ownc[k]) u[k] = ldc(&src[gyA[k] * W + gxc]);
        }

        // ---- 8 iterations as 2 fused groups of 4 (4-row halo) ----
        #pragma unroll
        for (int g = 0; g < 2; ++g) {
            #pragma unroll
            for (int q = 0; q < 4; q++) {
                xT[g][wv][q][lane] = u[q];          // rows r0..r0+3
                xB[g][wv][q][lane] = u[12 + q];     // rows r0+12..r0+15
            }
            __syncthreads();
            float wa[24], wb[24];
            #pragma unroll
            for (int q = 0; q < 4; q++) {
                wa[q]      = (wv > 0) ? xB[g][wv - 1][q][lane] : u[0];    // rows r0-4..r0-1
                wa[20 + q] = (wv < 3) ? xT[g][wv + 1][q][lane] : u[15];   // rows r0+16..r0+19
            }
            #pragma unroll
            for (int q = 0; q < 16; q++) wa[4 + q] = u[q];
            CSTEP(wa, wb, 1, 22);
            CSTEP(wb, wa, 2, 21);
            CSTEP(wa, wb, 3, 20);
            CSTEP(wb, wa, 4, 19);
            #pragma unroll
            for (int q = 0; q < 16; q++) u[q] = wa[4 + q];
        }

        if (t < 8) {
            float* dst = (t & 1) ? Tb1 : Tb0;
            // ring-store only: all any neighbor ever reads (8-deep overlap)
            #pragma unroll
            for (int k = 0; k < 16; k++) {
                if (ringk[k]) stc(&dst[(yb + r0 + k) * W + xb + lane], u[k]);
            }
            asm volatile("s_waitcnt vmcnt(0)" ::: "memory");
            __syncthreads();
            if (tid == 0) stci(&dflag[me * 16], t);
        } else {
            #pragma unroll
            for (int k = 0; k < 16; k++) {
                if (ownc[k]) ypb[(yb + r0 + k) * W + xb + lane] = u[k];
            }
        }
    }
}

extern "C" void kernel_launch(void* const* d_in, const int* in_sizes, int n_in,
                              void* d_out, int out_size, void* d_ws, size_t ws_size,
                              hipStream_t stream) {
    const float* guide   = (const float*)d_in[0];
    const float* initial = (const float*)d_in[1];
    float* y_pred = (float*)d_out;
    float* cv = y_pred + N_D;          // output 1
    float* ch = cv + N_CV;             // output 2

    uint8_t* w = (uint8_t*)d_ws;
    int* sync_ = (int*)w;              // wflag @0 (242*64 ints), dflag @16384 ints
    float* D  = (float*)(w + 131072);
    float* T0 = (float*)(w + 131072 + (size_t)N_D * 4);
    float* T1 = (float*)(w + 131072 + (size_t)2 * N_D * 4);

    (void)hipMemsetAsync(sync_, 0, 131072, stream);
    kall<<<dim3(121, NB), 256, 0, stream>>>(guide, initial, cv, ch, D, T0, T1, y_pred, sync_);
}

// Round 6
// 285.389 us; speedup vs baseline: 2.1918x; 1.0757x over previous
//
#include <hip/hip_runtime.h>
#include <stdint.h>

#define LDIFF 0.24f
#define MAGIC 0x5EED0B0B

constexpr int H = 512, W = 512, NB = 2;
constexpr int HW = H * W;              // 2^18
constexpr int N_D = NB * HW;           // 524288
constexpr int CVH = 511, CVW = 512;
constexpr int CHH = 512, CHW = 511;
constexpr int N_CV = NB * CVH * CVW;   // 523264
constexpr int NBLKS = 11;              // 11x11 blocks, step 48
constexpr int NBT = NB * 121;          // 242 workgroups <= 256 CUs -> co-resident

// LLC-coherent (cross-XCD) access: relaxed agent atomics = sc1 ops through the
// Infinity Cache. Validated R4-R9 (prior session) + R0/R5 here.
__device__ inline float ldc(const float* p) {
    return __hip_atomic_load(p, __ATOMIC_RELAXED, __HIP_MEMORY_SCOPE_AGENT);
}
__device__ inline void stc(float* p, float v) {
    __hip_atomic_store(p, v, __ATOMIC_RELAXED, __HIP_MEMORY_SCOPE_AGENT);
}
__device__ inline int ldci(const int* p) {
    return __hip_atomic_load(p, __ATOMIC_RELAXED, __HIP_MEMORY_SCOPE_AGENT);
}
__device__ inline void stci(int* p, int v) {
    __hip_atomic_store(p, v, __ATOMIC_RELAXED, __HIP_MEMORY_SCOPE_AGENT);
}

// wave64 DPP rotate/shift by 1 (VALU pipe, zero LDS traffic). Direction probed
// at runtime (dirL); the wavefront stencil's use (lf+rt) is direction-agnostic.
__device__ inline float rot_a(float x) {
    return __int_as_float(__builtin_amdgcn_update_dpp(0, __float_as_int(x), 0x134, 0xf, 0xf, false));
}
__device__ inline float rot_b(float x) {
    return __int_as_float(__builtin_amdgcn_update_dpp(0, __float_as_int(x), 0x13c, 0xf, 0xf, false));
}
__device__ inline float sh_a(float x) {
    return __int_as_float(__builtin_amdgcn_update_dpp(0, __float_as_int(x), 0x130, 0xf, 0xf, true));
}
__device__ inline float sh_b(float x) {
    return __int_as_float(__builtin_amdgcn_update_dpp(0, __float_as_int(x), 0x138, 0xf, 0xf, true));
}

// One fused B sub-iteration (algebraic c0 form: 7 VALU ops/row vs 9).
#define BSTEP(SRC, DST, LO, HI)                                                   \
    _Pragma("unroll")                                                             \
    for (int m = (LO); m <= (HI); m++) {                                          \
        float hs = rot_a(SRC[m]) + rot_b(SRC[m]);                                 \
        float vs = SRC[m - 1] + SRC[m + 1];                                       \
        DST[m] = fmaf(a, vs, fmaf(bc, hs, c0 * SRC[m]));                          \
    }

// One fused C sub-iteration. cve premultiplied by LDIFF; Pq/Qq carry the
// dirL-preswapped L*ch / L*chl so no per-row selects (verified both branches):
//   dirL : u = V + Lch*(rB-V) - Lchl*(V-rA)  -> P=Lch,  Q=Lchl
//   !dirL: u = V + Lch*(rA-V) - Lchl*(V-rB)  -> P=Lchl, Q=Lch
#define CSTEP(SRC, DST, LO, HI)                                                   \
    _Pragma("unroll")                                                             \
    for (int m = (LO); m <= (HI); m++) {                                          \
        float Vm = SRC[m] + cve[m] * (SRC[m + 1] - SRC[m])                        \
                          - cve[m - 1] * (SRC[m] - SRC[m - 1]);                   \
        float rA = rot_a(Vm), rB = rot_b(Vm);                                     \
        DST[m] = Vm + Pq[m] * (rB - Vm) - Qq[m] * (Vm - rA);                      \
    }

// ======================= ONE kernel, zero global barriers =======================
//  Protocol = R5 (proven). R6: (1) device-managed PARITY flag arrays — each
//  launch uses array p (zeroed by the previous launch), zeroes its own slots of
//  array p^1 at start, last-done block flips pword + sets magic; missing/
//  poisoned magic -> zero-both fallback. Removes the hipMemsetAsync dispatch:
//  the graph is ONE kernel. (2) BSTEP c0 algebra (-2 ops/row on the B chain).
//  (3) C coeff premult + dirL preswap (-5 ops/row on the C tail). (4) C poll
//  sleep 8->4.
__global__ __launch_bounds__(256) void kall(
    const float* __restrict__ guide, const float* __restrict__ initial,
    float* __restrict__ cv, float* __restrict__ ch,
    float* __restrict__ D, float* __restrict__ T0, float* __restrict__ T1,
    float* __restrict__ ypred, int* __restrict__ sync_)
{
    __shared__ float cvT[73 * 74];
    __shared__ float chT[73 * 74];
    __shared__ float xT[2][4][5][64];   // group-published top rows
    __shared__ float xB[2][4][5][64];   // group-published bottom rows
    __shared__ float red[12];
    __shared__ float prmS[3];
    __shared__ int ctlS[2];

    const int blk = blockIdx.x;           // 0..120
    const int i = blk / NBLKS, j = blk % NBLKS;
    const int b = blockIdx.y;
    const int tid = threadIdx.x;
    const int lane = tid & 63, wv = tid >> 6;
    const int r0 = wv * 16;
    const int me = b * 121 + blk;

    // ---- parity resolve + own-slot zeroing (off-path; drained once) ----
    // layout (ints): P0 wflag @0, P0 dflag @16384; P1 @32768/@49152;
    // ctrl: magic @65536, pword @65537, done @65538.
    if (tid == 0) {
        int mg = ldci(&sync_[65536]);
        int pw = ldci(&sync_[65537]);
        ctlS[0] = (mg == MAGIC) ? 1 : 0;
        ctlS[1] = (mg == MAGIC) ? (pw & 1) : 0;
    }
    __syncthreads();
    const int havemg = ctlS[0], par = ctlS[1];
    int* wflag = sync_ + par * 32768;     // (me)*64 + wv*16 (+0 strip, +8 full)
    int* dflag = wflag + 16384;           // (me)*16
    {
        int* oth = sync_ + (par ^ 1) * 32768;
        if (tid < 64) stci(&oth[me * 64 + tid], 0);
        if (tid < 16) stci(&oth[16384 + me * 16 + tid], 0);
        if (!havemg) {
            if (tid < 64) stci(&wflag[me * 64 + tid], 0);
            if (tid < 16) stci(&dflag[me * 16 + tid], 0);
            if (me == 0 && tid == 0) { stci(&sync_[65537], 0); stci(&sync_[65538], 0); }
        }
        asm volatile("s_waitcnt vmcnt(0)" ::: "memory");
    }
    __syncthreads();   // zeroes visible before any publish; consumers read >=10us later

    const int y0 = i * 48, x0 = j * 48;
    const int y1 = min(y0 + 64, 512), x1 = min(x0 + 64, 512);
    const int bh = y1 - y0, bw = x1 - x0;
    const int yb = y0 - 8, xb = x0 - 8;
    const float kinv = 1.0f / (0.03f * 0.03f);

    // ===== A1: local cv/ch (rows yb..yb+72, cols xb..xb+72; 0 outside valid) =====
    const float* gb = guide + (size_t)b * 3 * HW;
    for (int p = tid; p < 73 * 73; p += 256) {
        int rr = p / 73, cc2 = p - rr * 73;
        int y = yb + rr, x = xb + cc2;
        float cvv = 0.0f, chv = 0.0f;
        if (y >= 0 && y < 512 && x >= 0 && x < 512) {
            const float* g = gb + y * W + x;
            float g0 = g[0], g1 = g[HW], g2 = g[2 * HW];
            if (y < 511) {
                float d = (fabsf(g[W] - g0) + fabsf(g[HW + W] - g1) + fabsf(g[2 * HW + W] - g2)) * (1.0f / 3.0f);
                cvv = 1.0f / (1.0f + d * d * kinv);
            }
            if (x < 511) {
                float d = (fabsf(g[1] - g0) + fabsf(g[HW + 1] - g1) + fabsf(g[2 * HW + 1] - g2)) * (1.0f / 3.0f);
                chv = 1.0f / (1.0f + d * d * kinv);
            }
        }
        cvT[rr * 74 + cc2] = cvv;
        chT[rr * 74 + cc2] = chv;
    }
    __syncthreads();

    // ===== A2: write disjoint cv/ch output partitions (48x48 cores) =====
    // (store-issue only; flight time hides under A3 + the B dep wait)
    {
        int rcv = min(y0 + 48, CVH) - y0, ccv = min(x0 + 48, CVW) - x0;
        float* cvo = cv + b * CVH * CVW;
        for (int p = tid; p < rcv * ccv; p += 256) {
            int r = p / ccv, c = p - r * ccv;
            cvo[(y0 + r) * CVW + x0 + c] = cvT[(r + 8) * 74 + c + 8];
        }
        int rch = min(y0 + 48, CHH) - y0, cch = min(x0 + 48, CHW) - x0;
        float* cho = ch + b * CHH * CHW;
        for (int p = tid; p < rch * cch; p += 256) {
            int r = p / cch, c = p - r * cch;
            cho[(y0 + r) * CHW + x0 + c] = chT[(r + 8) * 74 + c + 8];
        }
    }

    // ===== A3: params — wave butterfly + 1 barrier =====
    float scv = 0.f, sch = 0.f, sun = 0.f;
    {
        int n = (bh - 1) * bw;
        for (int p = tid; p < n; p += 256) { int r = p / bw, c = p - r * bw; scv += cvT[(r + 8) * 74 + c + 8]; }
    }
    {
        int cols = bw - 1, n = bh * cols;
        for (int p = tid; p < n; p += 256) { int r = p / cols, c = p - r * cols; sch += chT[(r + 8) * 74 + c + 8]; }
    }
    const int ur = min(y1, 511) - y0, uc = min(x1, 511) - x0;
    {
        int n = ur * uc;
        for (int p = tid; p < n; p += 256) {
            int r = p / uc, c = p - r * uc;
            float s1 = 0.f, s2 = 0.f, t1 = 0.f, t2 = 0.f;
            #pragma unroll
            for (int dy = 0; dy < 3; dy++)
                #pragma unroll
                for (int dx = 0; dx < 3; dx++) {
                    float v = cvT[(r + 7 + dy) * 74 + c + 7 + dx]; s1 += v; s2 += v * v;
                    float w2 = chT[(r + 7 + dy) * 74 + c + 7 + dx]; t1 += w2; t2 += w2 * w2;
                }
            float m = s1 * (1.0f / 9.0f);
            float vcv = s2 * (1.0f / 9.0f) - m * m;
            m = t1 * (1.0f / 9.0f);
            float vch = t2 * (1.0f / 9.0f) - m * m;
            if (vcv < 0.1f && vch < 0.1f) sun += 1.f;
        }
    }
    #pragma unroll
    for (int m = 1; m < 64; m <<= 1) {
        scv += __shfl_xor(scv, m);
        sch += __shfl_xor(sch, m);
        sun += __shfl_xor(sun, m);
    }
    if (lane == 0) { red[wv * 3] = scv; red[wv * 3 + 1] = sch; red[wv * 3 + 2] = sun; }
    __syncthreads();
    if (tid == 0) {
        float a0 = red[0] + red[3] + red[6] + red[9];
        float a1 = red[1] + red[4] + red[7] + red[10];
        float a2 = red[2] + red[5] + red[8] + red[11];
        prmS[0] = a0 / (float)((bh - 1) * bw);
        prmS[1] = a1 / (float)(bh * (bw - 1));
        prmS[2] = (a2 / (float)(ur * uc) > 0.7f) ? 1.0f : 0.0f;
    }
    __syncthreads();

    // DPP direction probe (wave-uniform)
    int prb = __builtin_amdgcn_update_dpp(0, lane, 0x134, 0xf, 0xf, false);
    const bool dirL = (prb == ((lane + 63) & 63));

    const bool cond = prmS[2] > 0.5f;
    const float a = LDIFF * prmS[0], bc = LDIFF * prmS[1];
    const float c0 = 1.0f - 2.0f * a - 2.0f * bc;
    float* Db = D + b * HW;
    const float* ini = initial + b * HW;

    // ===== B: wavefront (split-publish, per-wave deps, fused 2x5 groups) =====
    const int mh = bh - 1, mw = bw - 1;
    const int ccw = lane & mw;

    if (!cond) {
        // region unchanged: write my non-strip region from `initial`
        #pragma unroll
        for (int k = 0; k < 16; k++) {
            int r = r0 + k;
            if (r < bh && (i == 0 || r >= 16) && lane < bw && (j == 0 || lane >= 16)) {
                int ad = (y0 + r) * W + x0 + lane;
                stc(&Db[ad], ini[ad]);
            }
        }
        asm volatile("s_waitcnt vmcnt(0)" ::: "memory");
        if (lane == 0) {
            stci(&wflag[me * 64 + wv * 16], 1);       // strip flag
            stci(&wflag[me * 64 + wv * 16 + 8], 1);   // full flag
        }
    } else {
        float u[16], orig[16];
        int addr[16]; bool fD[16];
        #pragma unroll
        for (int k = 0; k < 16; k++) {
            int rr = (r0 + k) & mh;
            addr[k] = (y0 + rr) * W + x0 + ccw;
            fD[k] = (i > 0 && rr < 16) || (j > 0 && ccw < 16);
            if (!fD[k]) orig[k] = ini[addr[k]];     // prefetch interior pre-wait
        }
        // ---- per-wave dep poll on STRIP flags (row-matched; no block barrier) ----
        {
            const int Lw = (r0 & mh) >> 4;                    // L wave covering my rows
            const bool needU = (i > 0) && ((r0 & mh) < 16);   // my rows include 0..15
            bool need = false;
            const int* fp = &wflag[me * 64];
            if (lane == 0) {
                if (j > 0) { need = true; fp = &wflag[(me - 1) * 64 + Lw * 16]; }
            } else if (lane == 1) {
                if (needU) { need = true; fp = &wflag[(me - NBLKS) * 64 + 3 * 16]; }
            } else if (lane == 2) {
                if (needU && j < 10) { need = true; fp = &wflag[(me - NBLKS + 1) * 64 + 3 * 16]; }
            } else if (lane == 3) {
                if (needU && j > 0) { need = true; fp = &wflag[(me - NBLKS - 1) * 64 + 3 * 16]; }
            }
            while (true) {
                int v = need ? ldci(fp) : 1;
                if (__ballot(v == 0) == 0) break;
                __builtin_amdgcn_s_sleep(0);
            }
        }
        #pragma unroll
        for (int k = 0; k < 16; k++) if (fD[k]) orig[k] = ldc(&Db[addr[k]]);
        #pragma unroll
        for (int k = 0; k < 16; k++) u[k] = orig[k];

        // ---- 10 iterations as 2 fused groups of 5 (5-row periodic halo) ----
        float wa[26], wb[26];
        #pragma unroll
        for (int g = 0; g < 2; ++g) {
            #pragma unroll
            for (int q = 0; q < 5; q++) {
                xT[g][wv][q][lane] = u[q];          // rows r0..r0+4
                xB[g][wv][q][lane] = u[11 + q];     // rows r0+11..r0+15
            }
            __syncthreads();
            #pragma unroll
            for (int q = 0; q < 5; q++) {
                wa[q]      = xB[g][(wv + 3) & 3][q][lane];   // rows r0-5..r0-1
                wa[21 + q] = xT[g][(wv + 1) & 3][q][lane];   // rows r0+16..r0+20
            }
            #pragma unroll
            for (int q = 0; q < 16; q++) wa[5 + q] = u[q];
            BSTEP(wa, wb, 1, 24);
            BSTEP(wb, wa, 2, 23);
            BSTEP(wa, wb, 3, 22);
            BSTEP(wb, wa, 4, 21);
            BSTEP(wa, wb, 5, 20);
            #pragma unroll
            for (int q = 0; q < 16; q++) u[q] = wb[5 + q];
        }

        // blend into final values
        #pragma unroll
        for (int k = 0; k < 16; k++) {
            int r = r0 + k;
            float byw = (y0 > 0 && r < 16) ? (float)r * (1.0f / 16.0f) : 1.0f;
            float bxw = (x0 > 0 && lane < 16) ? (float)lane * (1.0f / 16.0f) : 1.0f;
            float wgt = byw * bxw;
            u[k] = orig[k] * (1.0f - wgt) + u[k] * wgt;
        }
        // 1) outgoing strips (right 16-col if j<10; bottom 16-row) -> tiny drain -> flagA
        #pragma unroll
        for (int k = 0; k < 16; k++) {
            int r = r0 + k;
            bool in = (r < bh && lane < bw);
            bool sc = (bw == 64 && lane >= 48) || (r >= 48);
            if (in && sc) stc(&Db[(y0 + r) * W + x0 + lane], u[k]);
        }
        asm volatile("s_waitcnt vmcnt(0)" ::: "memory");
        if (lane == 0) stci(&wflag[me * 64 + wv * 16], 1);       // strip flag (chain)
        // 2) interior -> drain -> flagB (gates C t=1 only)
        #pragma unroll
        for (int k = 0; k < 16; k++) {
            int r = r0 + k;
            bool in = (r < bh && lane < bw);
            bool sc = (bw == 64 && lane >= 48) || (r >= 48);
            if (in && !sc) stc(&Db[(y0 + r) * W + x0 + lane], u[k]);
        }
        asm volatile("s_waitcnt vmcnt(0)" ::: "memory");
        if (lane == 0) stci(&wflag[me * 64 + wv * 16 + 8], 1);   // full flag
    }
    __syncthreads();   // all waves published; own D region complete for phase C

    // ===== C: diffusion, 8 stages x (2 fused groups of 4), reg-carry + ring-store =====
    const int cx = xb + lane;
    const int gxc = min(max(cx, 0), 511);
    int gyA[16];
    #pragma unroll
    for (int k = 0; k < 16; k++) {
        int cy = yb + r0 + k;
        gyA[k] = min(max(cy, 0), 511);
    }
    // extended coefficient cache (rows r0+m-4, m=0..23), premultiplied by LDIFF,
    // dirL preswapped into Pq/Qq (see CSTEP derivation above)
    float cve[24], Pq[24], Qq[24];
    #pragma unroll
    for (int m = 0; m < 24; m++) {
        int rr = r0 + m - 4;                 // max 48+19 = 67 < 73
        bool ok = (rr >= 0);
        float cvv = ok ? cvT[rr * 74 + lane] : 0.0f;
        float chh = ok ? chT[rr * 74 + lane] : 0.0f;
        float chl = dirL ? sh_a(chh) : sh_b(chh);   // lane0 -> 0 (halo col)
        cve[m] = LDIFF * cvv;
        Pq[m] = LDIFF * (dirL ? chh : chl);
        Qq[m] = LDIFF * (dirL ? chl : chh);
    }

    float* Tb0 = T0 + b * HW;
    float* Tb1 = T1 + b * HW;
    float* ypb = ypred + b * HW;

    // own-core / ring classification. Core = 48x48 (or clipped) tile exactly
    // tiling the image; window rows/cols 8.. map to core rows/cols 0..
    const int coreh = min(48, 512 - y0), corew = min(48, 512 - x0);
    const bool laneC = (lane >= 8) && (lane < 8 + corew);
    bool ownc[16], ringk[16];
    #pragma unroll
    for (int k = 0; k < 16; k++) {
        int wr = r0 + k;
        ownc[k] = laneC && (wr >= 8) && (wr < 8 + coreh);
        int cr = wr - 8, cl = lane - 8;
        ringk[k] = ownc[k] && (cr < 8 || cr >= coreh - 8 || cl < 8 || cl >= corew - 8);
    }

    float u[16];
    for (int t = 1; t <= 8; t++) {
        if (wv == 0) {
            bool need = false;
            const int* fp = &wflag[me * 64];
            int thr = 1;
            if (t == 1) {
                if (lane < 36) {
                    int nb = lane >> 2;
                    int di = nb / 3 - 1, dj = nb % 3 - 1;
                    int ni = i + di, nj = j + dj;
                    if ((di | dj) != 0 && ni >= 0 && ni < NBLKS && nj >= 0 && nj < NBLKS) {
                        need = true;
                        fp = &wflag[(b * 121 + ni * NBLKS + nj) * 64 + (lane & 3) * 16 + 8];  // FULL flags
                    }
                }
            } else {
                thr = t - 1;
                if (lane < 9) {
                    int di = lane / 3 - 1, dj = lane % 3 - 1;
                    int ni = i + di, nj = j + dj;
                    if ((di | dj) != 0 && ni >= 0 && ni < NBLKS && nj >= 0 && nj < NBLKS) {
                        need = true;
                        fp = &dflag[(b * 121 + ni * NBLKS + nj) * 16];
                    }
                }
            }
            while (true) {
                int v = need ? ldci(fp) : 0x7fffffff;
                if (__ballot(v < thr) == 0) break;
                __builtin_amdgcn_s_sleep(4);
            }
        }
        __syncthreads();
        const float* src = (t == 1) ? Db : (((t - 1) & 1) ? Tb1 : Tb0);
        if (t == 1) {
            #pragma unroll
            for (int k = 0; k < 16; k++) u[k] = ldc(&src[gyA[k] * W + gxc]);
        } else {
            // reg-carry: own-core cells already in u[]; reload only halo cells
            #pragma unroll
            for (int k = 0; k < 16; k++) if (!ownc[k]) u[k] = ldc(&src[gyA[k] * W + gxc]);
        }

        // ---- 8 iterations as 2 fused groups of 4 (4-row halo) ----
        #pragma unroll
        for (int g = 0; g < 2; ++g) {
            #pragma unroll
            for (int q = 0; q < 4; q++) {
                xT[g][wv][q][lane] = u[q];          // rows r0..r0+3
                xB[g][wv][q][lane] = u[12 + q];     // rows r0+12..r0+15
            }
            __syncthreads();
            float wa[24], wb[24];
            #pragma unroll
            for (int q = 0; q < 4; q++) {
                wa[q]      = (wv > 0) ? xB[g][wv - 1][q][lane] : u[0];    // rows r0-4..r0-1
                wa[20 + q] = (wv < 3) ? xT[g][wv + 1][q][lane] : u[15];   // rows r0+16..r0+19
            }
            #pragma unroll
            for (int q = 0; q < 16; q++) wa[4 + q] = u[q];
            CSTEP(wa, wb, 1, 22);
            CSTEP(wb, wa, 2, 21);
            CSTEP(wa, wb, 3, 20);
            CSTEP(wb, wa, 4, 19);
            #pragma unroll
            for (int q = 0; q < 16; q++) u[q] = wa[4 + q];
        }

        if (t < 8) {
            float* dst = (t & 1) ? Tb1 : Tb0;
            // ring-store only: all any neighbor ever reads (8-deep overlap)
            #pragma unroll
            for (int k = 0; k < 16; k++) {
                if (ringk[k]) stc(&dst[(yb + r0 + k) * W + xb + lane], u[k]);
            }
            asm volatile("s_waitcnt vmcnt(0)" ::: "memory");
            __syncthreads();
            if (tid == 0) stci(&dflag[me * 16], t);
        } else {
            #pragma unroll
            for (int k = 0; k < 16; k++) {
                if (ownc[k]) ypb[(yb + r0 + k) * W + xb + lane] = u[k];
            }
        }
    }

    // ---- launch-complete accounting: last block flips parity, arms magic ----
    __syncthreads();
    if (tid == 0) {
        int n = __hip_atomic_fetch_add(&sync_[65538], 1, __ATOMIC_RELAXED, __HIP_MEMORY_SCOPE_AGENT);
        if (n == NBT - 1) {
            stci(&sync_[65538], 0);
            stci(&sync_[65537], par ^ 1);
            stci(&sync_[65536], MAGIC);
        }
    }
}

extern "C" void kernel_launch(void* const* d_in, const int* in_sizes, int n_in,
                              void* d_out, int out_size, void* d_ws, size_t ws_size,
                              hipStream_t stream) {
    const float* guide   = (const float*)d_in[0];
    const float* initial = (const float*)d_in[1];
    float* y_pred = (float*)d_out;
    float* cv = y_pred + N_D;          // output 1
    float* ch = cv + N_CV;             // output 2

    uint8_t* w = (uint8_t*)d_ws;
    int* sync_ = (int*)w;              // 2 parity flag arrays (128 KB each) + ctrl
    float* D  = (float*)(w + 262656);  // after 256 KB sync + ctrl line (aligned)
    float* T0 = D + N_D;
    float* T1 = T0 + N_D;
    // total ws use: 256.5 KB + 3 * 2 MB ~= 6.5 MB; no memset: single-dispatch graph

    kall<<<dim3(121, NB), 256, 0, stream>>>(guide, initial, cv, ch, D, T0, T1, y_pred, sync_);
}